// Round 15
// baseline (222.378 us; speedup 1.0000x reference)
//
#include <hip/hip_runtime.h>
#include <stdint.h>

#define NEGF (-1e30f)

typedef unsigned short ushort_t;
typedef unsigned char uchar_t;
typedef __attribute__((ext_vector_type(2))) long v2i64;
typedef __attribute__((ext_vector_type(4))) float f32x4;
typedef __attribute__((ext_vector_type(16))) float f32x16;

constexpr int cB = 4, cT = 256, cU = 64, cU1 = 65, cV = 1024, cF = 80, cH = 512, cJ = 512;
constexpr int cM = cB * cT * cU1; // 66560
constexpr int cTU = cT * cU1;     // 16640 (per-batch (u,t) plane: u*256+t)
constexpr float LOG2E = 1.4426950408889634f;

// Padé(2,2) tanh + clamp: max err ~0.016, far below fp8-e4m3 half-step; no v_exp.
__device__ __forceinline__ float tanh_fast(float x){
  float t = x * x;
  float num = x * (27.f + t);
  float den = fmaf(9.f, t, 27.f);
  float r = num * __builtin_amdgcn_rcpf(den);
  return fminf(1.f, fmaxf(-1.f, r));
}

// log2-domain logadd: v_exp_f32/v_log_f32 ARE base-2 -> no ln2 scaling muls.
__device__ __forceinline__ float logadd2(float x, float y){
  float m = fmaxf(x, y);
  return m + __builtin_amdgcn_logf(1.f + __builtin_amdgcn_exp2f(-fabsf(x - y)));
}

// wave shift-right-by-1 via DPP (lane i <- lane i-1); invalid lane 0 reads 0.0f
// (bound_ctrl:0). 2-cycle VALU op on k_dp's serial A->A critical path.
__device__ __forceinline__ float wshr1(float x){
  return __int_as_float(__builtin_amdgcn_mov_dpp(__float_as_int(x),
                                                 0x138, 0xF, 0xF, true));
}

__device__ __forceinline__ int pk8(float a, float b, float c, float d){
  int v = __builtin_amdgcn_cvt_pk_fp8_f32(a, b, 0, false);
  v = __builtin_amdgcn_cvt_pk_fp8_f32(c, d, v, true);
  return v;
}

// ------------- fused prologue: 4 independent jobs in one dispatch -------------
// bid 0..255  : e[4 rows] = (inputs @ W_enc) @ W_jenc, block-local two-stage
// bid 256..385: dmatb(260,512) = emb[padded] @ W_jdec + b_j
// bid 386..417: WTf8 fp8 32x32x16 fragment transpose of 32*W_out
//               layout: [(bn*4+nt32)*16+j][lane]*16B; bytes0..7: k=32j+kh*8+b,
//               col=bn*128+nt32*32+(lane&31); bytes8..15: k+16. (kh=lane>>5)
// bid 418..482: zero S[cM]; bid 418 also zeroes out[0] (k_dp atomic target)
__global__ __launch_bounds__(256) void k_pre(
    const float* __restrict__ inputs,
    const float* __restrict__ W_enc, const float* __restrict__ W_jenc,
    const float* __restrict__ emb, const int* __restrict__ targets,
    const float* __restrict__ W_jdec, const float* __restrict__ b_j,
    float* __restrict__ dmatb, float* __restrict__ e,
    const float* __restrict__ W_out, uchar_t* __restrict__ WTf8,
    float* __restrict__ S, float* __restrict__ out_loss)
{
  __shared__ float sA[4][512];
  __shared__ float sIn[4][80];
  int bid = blockIdx.x;
  int tid = threadIdx.x;

  if (bid < 256){
    // ---- e rows m0..m0+3 ----
    int m0 = bid * 4;
    // r20 BUG FIX: 320 elements with 256 threads needs a strided loop (the
    // single `if (tid < 320)` left sIn[3][16..79] uninitialized -> absmax 16).
    for (int i = tid; i < 320; i += 256)
      sIn[i / 80][i % 80] = inputs[m0 * 80 + i];
    __syncthreads();
    int c0 = tid, c1 = tid + 256;
    float a00 = 0.f, a01 = 0.f, a10 = 0.f, a11 = 0.f;
    float a20 = 0.f, a21 = 0.f, a30 = 0.f, a31 = 0.f;
#pragma unroll 8
    for (int k = 0; k < 80; k++){
      float w0 = W_enc[(size_t)k * 512 + c0];
      float w1 = W_enc[(size_t)k * 512 + c1];
      a00 = fmaf(sIn[0][k], w0, a00); a01 = fmaf(sIn[0][k], w1, a01);
      a10 = fmaf(sIn[1][k], w0, a10); a11 = fmaf(sIn[1][k], w1, a11);
      a20 = fmaf(sIn[2][k], w0, a20); a21 = fmaf(sIn[2][k], w1, a21);
      a30 = fmaf(sIn[3][k], w0, a30); a31 = fmaf(sIn[3][k], w1, a31);
    }
    sA[0][c0] = a00; sA[0][c1] = a01;
    sA[1][c0] = a10; sA[1][c1] = a11;
    sA[2][c0] = a20; sA[2][c1] = a21;
    sA[3][c0] = a30; sA[3][c1] = a31;
    __syncthreads();
    float b00 = 0.f, b01 = 0.f, b10 = 0.f, b11 = 0.f;
    float b20 = 0.f, b21 = 0.f, b30 = 0.f, b31 = 0.f;
#pragma unroll 8
    for (int k = 0; k < 512; k++){
      float w0 = W_jenc[(size_t)k * 512 + c0];
      float w1 = W_jenc[(size_t)k * 512 + c1];
      b00 = fmaf(sA[0][k], w0, b00); b01 = fmaf(sA[0][k], w1, b01);
      b10 = fmaf(sA[1][k], w0, b10); b11 = fmaf(sA[1][k], w1, b11);
      b20 = fmaf(sA[2][k], w0, b20); b21 = fmaf(sA[2][k], w1, b21);
      b30 = fmaf(sA[3][k], w0, b30); b31 = fmaf(sA[3][k], w1, b31);
    }
    e[(size_t)(m0 + 0) * 512 + c0] = b00; e[(size_t)(m0 + 0) * 512 + c1] = b01;
    e[(size_t)(m0 + 1) * 512 + c0] = b10; e[(size_t)(m0 + 1) * 512 + c1] = b11;
    e[(size_t)(m0 + 2) * 512 + c0] = b20; e[(size_t)(m0 + 2) * 512 + c1] = b21;
    e[(size_t)(m0 + 3) * 512 + c0] = b30; e[(size_t)(m0 + 3) * 512 + c1] = b31;
  } else if (bid < 386){
    // ---- dmatb = emb[padded] @ W_jdec + b_j ----
    int id = bid - 256;                  // 0..129
    int bx = id & 1, by = id >> 1;
    int m0 = by * 4;
    int col = bx * 256 + tid;
    for (int i = tid; i < 4 * 512; i += 256){
      int r = i >> 9, c = i & 511;
      int row = m0 + r;
      int b = row / cU1, u = row % cU1;
      int src = (u == 0) ? 0 : targets[b * cU + (u - 1)];
      sA[r][c] = emb[(size_t)src * cH + c];
    }
    __syncthreads();
    float a0 = 0.f, a1 = 0.f, a2 = 0.f, a3 = 0.f;
#pragma unroll 8
    for (int k = 0; k < 512; k++){
      float bv = W_jdec[(size_t)k * cJ + col];
      a0 = fmaf(sA[0][k], bv, a0);
      a1 = fmaf(sA[1][k], bv, a1);
      a2 = fmaf(sA[2][k], bv, a2);
      a3 = fmaf(sA[3][k], bv, a3);
    }
    float bb = b_j[col];
    dmatb[(size_t)(m0 + 0) * cJ + col] = a0 + bb;
    dmatb[(size_t)(m0 + 1) * cJ + col] = a1 + bb;
    dmatb[(size_t)(m0 + 2) * cJ + col] = a2 + bb;
    dmatb[(size_t)(m0 + 3) * cJ + col] = a3 + bb;
  } else if (bid < 418){
    // ---- WTf8 32x32x16 fragments ----
    int id = bid - 386;                  // 0..31
    int bn = id & 7, jq = id >> 3;       // bn strip, jq = kpair quarter
    int lane = tid & 63, nt32 = tid >> 6;
    int c32 = lane & 31, kh = lane >> 5;
    int col = bn * 128 + nt32 * 32 + c32;
#pragma unroll
    for (int jj = 0; jj < 4; jj++){
      int j = jq * 4 + jj;
      unsigned p[4];
#pragma unroll
      for (int h = 0; h < 2; h++){
        int k0 = 32 * j + 16 * h + kh * 8;
        float w0 = W_out[(size_t)(k0 + 0) * cV + col] * 32.f;
        float w1 = W_out[(size_t)(k0 + 1) * cV + col] * 32.f;
        float w2 = W_out[(size_t)(k0 + 2) * cV + col] * 32.f;
        float w3 = W_out[(size_t)(k0 + 3) * cV + col] * 32.f;
        float w4 = W_out[(size_t)(k0 + 4) * cV + col] * 32.f;
        float w5 = W_out[(size_t)(k0 + 5) * cV + col] * 32.f;
        float w6 = W_out[(size_t)(k0 + 6) * cV + col] * 32.f;
        float w7 = W_out[(size_t)(k0 + 7) * cV + col] * 32.f;
        p[h * 2 + 0] = (unsigned)pk8(w0, w1, w2, w3);
        p[h * 2 + 1] = (unsigned)pk8(w4, w5, w6, w7);
      }
      uint4 pack; pack.x = p[0]; pack.y = p[1]; pack.z = p[2]; pack.w = p[3];
      *(uint4*)(WTf8 + (((size_t)(bn * 4 + nt32) * 16 + j) * 64 + lane) * 16) = pack;
    }
  } else {
    // ---- zero S: 65 blocks x 256 thr x 4 floats = 66560 ----
    int i = (bid - 418) * 1024 + tid * 4;
    float4 z; z.x = 0.f; z.y = 0.f; z.z = 0.f; z.w = 0.f;
    *(float4*)(S + i) = z;
    if (bid == 418 && tid == 0) out_loss[0] = 0.f;
  }
}

// ------------- H fp8 32x32x16 fragment-order, coalesced via LDS bounce -------------
// Hbf8 per bm tile: [(g*16+j)*64+lane]*16B; lane holds row = g*32+(lane&31),
// bytes0..7: k = 32j + (lane>>5)*8 + b; bytes8..15: k+16. g in 0..3 (32-row grp).
__global__ __launch_bounds__(256) void k_hf(const float* __restrict__ e,
                                            const float* __restrict__ dmatb,
                                            uchar_t* __restrict__ Hbf8){
  __shared__ uchar_t sH[32 * 520];    // 32 rows x 512 B, pad 8 B
  int tid = threadIdx.x;
  int wid = tid >> 6, lane = tid & 63;
  int c32 = lane & 31, kh = lane >> 5;
  int bm = blockIdx.x;
  int bu = bm >> 1, thalf = bm & 1;
  int b = bu / cU1;
  int t0 = thalf * 128;

  float dj[8];
  const float4* dp = (const float4*)(dmatb + (size_t)bu * cJ + lane * 8);
  float4 dA = dp[0], dB = dp[1];
  dj[0] = dA.x; dj[1] = dA.y; dj[2] = dA.z; dj[3] = dA.w;
  dj[4] = dB.x; dj[5] = dB.y; dj[6] = dB.z; dj[7] = dB.w;

  const float* erow0 = e + ((size_t)(b * cT + t0)) * cJ + lane * 8;
  uchar_t* outb = Hbf8 + (size_t)bm * 65536 + lane * 16;

  for (int g = 0; g < 4; g++){
#pragma unroll
    for (int rr = 0; rr < 8; rr++){
      int rloc = wid * 8 + rr;          // 0..31
      const float* ep = erow0 + ((size_t)(g * 32 + rloc)) * cJ;
      float4 e0 = *(const float4*)ep;
      float4 e1 = *(const float4*)(ep + 4);
      int v0 = pk8(tanh_fast(e0.x + dj[0]), tanh_fast(e0.y + dj[1]),
                   tanh_fast(e0.z + dj[2]), tanh_fast(e0.w + dj[3]));
      int v1 = pk8(tanh_fast(e1.x + dj[4]), tanh_fast(e1.y + dj[5]),
                   tanh_fast(e1.z + dj[6]), tanh_fast(e1.w + dj[7]));
      uint2 pk; pk.x = (unsigned)v0; pk.y = (unsigned)v1;
      *(uint2*)(sH + rloc * 520 + lane * 8) = pk;
    }
    __syncthreads();
#pragma unroll
    for (int jj = 0; jj < 4; jj++){
      int j = wid * 4 + jj;             // each wave emits 4 kpair fragments
      const uchar_t* src = sH + c32 * 520 + 32 * j + kh * 8;
      uint2 lo = *(const uint2*)(src);        // k = 32j + kh*8 .. +7
      uint2 hi = *(const uint2*)(src + 16);   // k + 16
      uint4 pack; pack.x = lo.x; pack.y = lo.y; pack.z = hi.x; pack.w = hi.y;
      *(uint4*)(outb + ((size_t)(g * 16 + j)) * 1024) = pack;
    }
    __syncthreads();
  }
}

// ------------- joint GEMM fp8 32x32x16: 64x64 wave tile, X/Y kpair pipeline -------------
// r15: shape switch 256x mfma_16x16x32 (5cy) -> 128x mfma_32x32x16 (8cy):
// matrix-pipe cycles 1280->1024 (-20%), ceiling 2047->2190 TF (+7%), MFMA
// issue count halved (more slots for loads). Fragment regs DROP 64->32 VGPR
// (safely under the ~80-VGPR spill wall proven by r2/r4/r8/r13). C/D map:
// col=lane&31, row=(reg&3)+8*(reg>>2)+4*(lane>>5) (m74/m101 verified).
// Epilogue: LDS partials redP[2][128][33] (write/read conflict-free).
__global__ __launch_bounds__(256, 3) void k_joint(
    const uchar_t* __restrict__ Hbf8, const uchar_t* __restrict__ WTf8,
    const float* __restrict__ b_out, const int* __restrict__ targets,
    float* __restrict__ S,
    float* __restrict__ blank_g, float* __restrict__ lbl_g)
{
  __shared__ float redP[2][128][33];   // 33792 B

  int tid = threadIdx.x;
  int wid = tid >> 6, lane = tid & 63;
  int c32 = lane & 31, kh = lane >> 5;
  int wm = wid & 1, wn = wid >> 1;
  int bid = blockIdx.x;
  int bm = ((bid >> 6) << 3) + (bid & 7);
  int bn = (bid >> 3) & 7;                       // 128-col strip
  int bu = bm >> 1, thalf = bm & 1;
  int b = bu / cU1, u = bu - b * cU1;
  int tg = (u < cU) ? targets[b * cU + u] : -1;
  int lin0 = bu * cT + thalf * 128;              // (b,u,t)-linear base

  f32x16 acc[2][2];
#pragma unroll
  for (int i = 0; i < 2; i++)
#pragma unroll
    for (int j = 0; j < 2; j++)
#pragma unroll
      for (int r = 0; r < 16; r++) acc[i][j][r] = 0.f;

  const uchar_t* aP = Hbf8 + (size_t)bm * 65536 + (size_t)wm * 32768 + lane * 16;
  const uchar_t* bP = WTf8 + (size_t)bn * 65536 + (size_t)wn * 32768 + lane * 16;

  v2i64 afX[2], bfX[2], afY[2], bfY[2];
#pragma unroll
  for (int mt = 0; mt < 2; mt++) afX[mt] = *(const v2i64*)(aP + mt * 16384);
#pragma unroll
  for (int nt = 0; nt < 2; nt++) bfX[nt] = *(const v2i64*)(bP + nt * 16384);

#pragma unroll
  for (int j2 = 0; j2 < 8; j2++){
    // ---- issue loads for kpair 2*j2+1 (Y) ahead of MFMA(X) ----
    {
      size_t jY = (size_t)(2 * j2 + 1) * 1024;
      afY[0] = *(const v2i64*)(aP + jY);
      afY[1] = *(const v2i64*)(aP + 16384 + jY);
      bfY[0] = *(const v2i64*)(bP + jY);
      bfY[1] = *(const v2i64*)(bP + 16384 + jY);
    }
#pragma unroll
    for (int h = 0; h < 2; h++)
#pragma unroll
      for (int mt = 0; mt < 2; mt++)
#pragma unroll
        for (int nt = 0; nt < 2; nt++)
          acc[mt][nt] = __builtin_amdgcn_mfma_f32_32x32x16_fp8_fp8(afX[mt][h], bfX[nt][h], acc[mt][nt], 0, 0, 0);
    if (j2 < 7){
      size_t jX = (size_t)(2 * j2 + 2) * 1024;
      afX[0] = *(const v2i64*)(aP + jX);
      afX[1] = *(const v2i64*)(aP + 16384 + jX);
      bfX[0] = *(const v2i64*)(bP + jX);
      bfX[1] = *(const v2i64*)(bP + 16384 + jX);
    }
#pragma unroll
    for (int h = 0; h < 2; h++)
#pragma unroll
      for (int mt = 0; mt < 2; mt++)
#pragma unroll
        for (int nt = 0; nt < 2; nt++)
          acc[mt][nt] = __builtin_amdgcn_mfma_f32_32x32x16_fp8_fp8(afY[mt][h], bfY[nt][h], acc[mt][nt], 0, 0, 0);
  }

  float bv[2];
#pragma unroll
  for (int nt = 0; nt < 2; nt++) bv[nt] = b_out[bn * 128 + wn * 64 + nt * 32 + c32] * LOG2E;

  bool ownL = (tg >= 0) && ((tg >> 7) == bn) && (((tg >> 6) & 1) == wn);
  int ntO = (tg >> 5) & 1;
  int tgc = tg & 31;
  const float descale2 = LOG2E / 32.f;  // undo *32 on W_out fp8 AND go log2-domain

#pragma unroll
  for (int mt = 0; mt < 2; mt++){
#pragma unroll
    for (int r = 0; r < 16; r++){
      // C/D: col = lane&31, row = (r&3) + 8*(r>>2) + 4*(lane>>5)  (m74/m101)
      int rl = wm * 64 + mt * 32 + (r & 3) + 8 * (r >> 2) + 4 * kh;
      float l0 = fmaf(acc[mt][0][r], descale2, bv[0]);
      float l1 = fmaf(acc[mt][1][r], descale2, bv[1]);
      if (bn == 0 && wn == 0 && c32 == 0) blank_g[lin0 + rl] = l0;
      if (ownL && c32 == tgc) lbl_g[lin0 + rl] = (ntO == 0) ? l0 : l1;
      redP[wn][rl][c32] = __builtin_amdgcn_exp2f(l0) + __builtin_amdgcn_exp2f(l1);
    }
  }
  __syncthreads();
  if (tid < 128){
    float a = 0.f;
#pragma unroll
    for (int j = 0; j < 32; j++) a += redP[0][tid][j] + redP[1][tid][j];
    atomicAdd(&S[lin0 + tid], a);
  }
}

// ------------- RNN-T alpha DP: phase-split producer/consumer + gmax truncation -------------
// (unchanged from the measured-202.9us r14 version)
__global__ __launch_bounds__(256) void k_dp(
    const float* __restrict__ S, const float* __restrict__ blank_g,
    const float* __restrict__ lbl_g,
    const int* __restrict__ in_len, const int* __restrict__ tgt_len,
    float* __restrict__ out)
{
  constexpr int G = 16;        // g-steps per chunk
  __shared__ float sbb[cTU];   // 65 KB, (u,t): index u*256+t  (log2 domain)
  __shared__ float slb[cTU];   // 65 KB
  __shared__ float sS[256];    // alpha[t][63] history (lane 63)
  __shared__ float cC0[G * 64], cC1[G * 64], cC2[G * 64];
  __shared__ float cOA[G * 64], cOB[G * 64];
  int tid = threadIdx.x;
  int b = blockIdx.x;
  int tl  = tgt_len[b];                // 32..64
  size_t base = (size_t)b * cTU;
  for (int i = tid; i < cTU / 4; i += 256){
    int row = i >> 6;                  // float4 never crosses a 256-elem row
    if (row > tl) continue;            // rows > tl unread by any live lane
    float4 sv = ((const float4*)(S + base))[i];
    float4 bvv = ((const float4*)(blank_g + base))[i];
    float4 ls;
    ls.x = __builtin_amdgcn_logf(sv.x); ls.y = __builtin_amdgcn_logf(sv.y);
    ls.z = __builtin_amdgcn_logf(sv.z); ls.w = __builtin_amdgcn_logf(sv.w);
    float4 bo;
    bo.x = bvv.x - ls.x; bo.y = bvv.y - ls.y;
    bo.z = bvv.z - ls.z; bo.w = bvv.w - ls.w;
    ((float4*)sbb)[i] = bo;
    float4 lo;
    if (row < tl){
      float4 lv = ((const float4*)(lbl_g + base))[i];
      lo.x = lv.x - ls.x; lo.y = lv.y - ls.y;
      lo.z = lv.z - ls.z; lo.w = lv.w - ls.w;
    } else {
      lo.x = NEGF; lo.y = NEGF; lo.z = NEGF; lo.w = NEGF;
    }
    ((float4*)slb)[i] = lo;
  }
  __syncthreads();

  int til = in_len[b] - 1;
  bool cap64 = (tl == 64);
  int u = tid;                         // meaningful for tid<64
  bool isTL = (u == tl);
  float fb = (tid < 64) ? sbb[(u << 8) + til] : 0.f;

  // last diagonal needed: res captures at g<=ceil((til+tl)/2); sS fills
  // (cap64 path) need g<=ceil((til+62)/2). +2 safety; cap at 159.
  int need = til + tl;
  if (cap64 && til + 62 > need) need = til + 62;
  int gmax = (need >> 1) + 2;
  if (gmax > 159) gmax = 159;
  int nph = (gmax + G - 1) / G;        // block-uniform

  float A = (u == 0) ? 0.f : NEGF;     // alpha on even diagonal d = 2g (log2)
  float res = 0.f;

  auto ld = [&](const float* p, int i, bool ok) -> float {
    float x = p[i & 255];              // wrap stays inside sbb/slb
    return (ok & ((unsigned)i < 256u)) ? x : NEGF;
  };

  for (int p = 0; p < nph; p++){
    // ---- fill phase: all 256 threads precompute C/o arrays for this chunk ----
    for (int w = tid; w < G * 64; w += 256){
      int gg = w >> 6, uu = w & 63;
      int g = p * G + gg;              // g>=gmax entries filled but never read
      int i0 = 2 * g - uu;
      bool v1 = (uu >= 1), v2 = (uu >= 2);
      const float* pbu  = sbb + (uu << 8);
      const float* pbu1 = sbb + ((v1 ? uu - 1 : 0) << 8);
      const float* plu1 = slb + ((v1 ? uu - 1 : 0) << 8);
      const float* plu2 = slb + ((v2 ? uu - 2 : 0) << 8);
      float o0 = ld(pbu,  i0,     true);   // bb[t-2][u]
      float o1 = ld(pbu,  i0 + 1, true);   // bb[t-1][u]
      float o2 = ld(plu1, i0 + 1, v1);     // lb[t-1][u-1]
      float o3 = ld(pbu1, i0 + 1, v1);     // bb[t-1][u-1]
      float o4 = ld(plu1, i0 + 2, v1);     // lb[t][u-1]
      float o5 = ld(plu2, i0 + 2, v2);     // lb[t][u-2]
      cC0[w] = o0 + o1;
      cC1[w] = logadd2(o2 + o1, o3 + o4);
      cC2[w] = o5 + o4;
      cOA[w] = o0;
      cOB[w] = o2;
    }
    __syncthreads();
    // ---- consume phase: wave 0 runs G recurrence steps ----
    if (tid < 64){
      float c0v = cC0[u], c1v = cC1[u], c2v = cC2[u];
      float oAv = cOA[u], oBv = cOB[u];
#pragma unroll
      for (int gg = 0; gg < G; gg++){
        int g = p * G + gg;
        int nx = (gg + 1 < G) ? ((gg + 1) << 6) + u : (gg << 6) + u;
        float nc0 = cC0[nx], nc1 = cC1[nx], nc2 = cC2[nx];
        float noA = cOA[nx], noB = cOB[nx];
        if (g < gmax){
          float up1 = wshr1(A);
          float up2 = wshr1(up1);
          int i0 = 2 * g - u;
          float Amid = logadd2(A + oAv, up1 + oBv);
          bool tv1 = ((unsigned)(i0 + 1) < 256u);
          Amid = tv1 ? Amid : NEGF;
          float a0 = A + c0v, a1 = up1 + c1v, a2 = up2 + c2v;
          float m3 = fmaxf(fmaxf(a0, a1), a2);          // v_max3
          float s3 = __builtin_amdgcn_exp2f(a0 - m3) + __builtin_amdgcn_exp2f(a1 - m3)
                   + __builtin_amdgcn_exp2f(a2 - m3);
          float Anew = m3 + __builtin_amdgcn_logf(s3);
          bool tv2 = ((unsigned)(i0 + 2) < 256u);
          Anew = tv2 ? Anew : NEGF;
          if (isTL && (i0 + 1) == til) res = Amid + fb;
          if (isTL && (i0 + 2) == til) res = Anew + fb;
          if (u == 63){
            if (tv1) sS[i0 + 1] = Amid;
            if (tv2) sS[i0 + 2] = Anew;
          }
          A = Anew;
        }
        c0v = nc0; c1v = nc1; c2v = nc2; oAv = noA; oBv = noB;
      }
    }
    __syncthreads();                   // protect cArr from next fill
  }

  if (tid >= 64) return;

  if (cap64){
    const float* pb64 = sbb + (64 << 8);
    const float* pl63 = slb + (63 << 8);
    float A64 = sS[0] + pl63[0];       // alpha[0][64]
    for (int t = 1; t <= til; t++)
      A64 = logadd2(A64 + pb64[t - 1], sS[t] + pl63[t]);
    if (u == 0) res = A64 + pb64[til];
  }

  // butterfly-sum broadcasts the single captured value (others hold 0)
  res += __shfl_xor(res, 1, 64);
  res += __shfl_xor(res, 2, 64);
  res += __shfl_xor(res, 4, 64);
  res += __shfl_xor(res, 8, 64);
  res += __shfl_xor(res, 16, 64);
  res += __shfl_xor(res, 32, 64);
  if (u == 0) atomicAdd(out, -0.17328679513998632f * res);  // -0.25 * ln2 (log2->ln)
}

extern "C" void kernel_launch(void* const* d_in, const int* in_sizes, int n_in,
                              void* d_out, int out_size, void* d_ws, size_t ws_size,
                              hipStream_t stream)
{
  (void)in_sizes; (void)n_in; (void)out_size; (void)ws_size;
  const float* inputs = (const float*)d_in[0];   // (4,256,80)
  const float* W_enc  = (const float*)d_in[1];   // (80,512)
  const float* emb    = (const float*)d_in[2];   // (1024,512)
  const float* W_jenc = (const float*)d_in[3];   // (512,512)
  const float* W_jdec = (const float*)d_in[4];   // (512,512)
  const float* b_j    = (const float*)d_in[5];   // (512)
  const float* W_out  = (const float*)d_in[6];   // (512,1024)
  const float* b_out  = (const float*)d_in[7];   // (1024)
  const int* targets  = (const int*)d_in[8];     // (4,64)
  const int* in_len   = (const int*)d_in[9];     // (4)
  const int* tgt_len  = (const int*)d_in[10];    // (4)

  char* w = (char*)d_ws;
  auto alloc = [&](size_t bytes){ char* p = w; w += (bytes + 255) & ~(size_t)255; return p; };
  float* e       = (float*)alloc((size_t)1024 * 512 * 4);
  float* dmatb   = (float*)alloc((size_t)260 * 512 * 4);
  float* blank_g = (float*)alloc((size_t)cM * 4);
  float* lbl_g   = (float*)alloc((size_t)cM * 4);
  float* S       = (float*)alloc((size_t)cM * 4);
  uchar_t* Hbf8  = (uchar_t*)alloc((size_t)520 * 65536);
  uchar_t* WTf8  = (uchar_t*)alloc((size_t)8 * 65536);

  k_pre<<<483, 256, 0, stream>>>(inputs, W_enc, W_jenc, emb, targets, W_jdec, b_j,
                                 dmatb, e, W_out, WTf8, S, (float*)d_out);
  k_hf<<<520, 256, 0, stream>>>(e, dmatb, Hbf8);
  k_joint<<<4160, 256, 0, stream>>>(Hbf8, WTf8, b_out, targets, S, blank_g, lbl_g);
  k_dp<<<4, 256, 0, stream>>>(S, blank_g, lbl_g, in_len, tgt_len, (float*)d_out);
}

// Round 16
// 202.066 us; speedup vs baseline: 1.1005x; 1.1005x over previous
//
#include <hip/hip_runtime.h>
#include <stdint.h>

#define NEGF (-1e30f)

typedef unsigned short ushort_t;
typedef unsigned char uchar_t;
typedef __attribute__((ext_vector_type(2))) long v2i64;
typedef __attribute__((ext_vector_type(4))) float f32x4;

constexpr int cB = 4, cT = 256, cU = 64, cU1 = 65, cV = 1024, cF = 80, cH = 512, cJ = 512;
constexpr int cM = cB * cT * cU1; // 66560
constexpr int cTU = cT * cU1;     // 16640 (per-batch (u,t) plane: u*256+t)
constexpr float LOG2E = 1.4426950408889634f;

// Padé(2,2) tanh + clamp: max err ~0.016, far below fp8-e4m3 half-step; no v_exp.
__device__ __forceinline__ float tanh_fast(float x){
  float t = x * x;
  float num = x * (27.f + t);
  float den = fmaf(9.f, t, 27.f);
  float r = num * __builtin_amdgcn_rcpf(den);
  return fminf(1.f, fmaxf(-1.f, r));
}

// log2-domain logadd: v_exp_f32/v_log_f32 ARE base-2 -> no ln2 scaling muls.
__device__ __forceinline__ float logadd2(float x, float y){
  float m = fmaxf(x, y);
  return m + __builtin_amdgcn_logf(1.f + __builtin_amdgcn_exp2f(-fabsf(x - y)));
}

// wave shift-right-by-1 via DPP (lane i <- lane i-1); invalid lane 0 reads 0.0f
// (bound_ctrl:0). 2-cycle VALU op on k_dp's serial A->A critical path.
__device__ __forceinline__ float wshr1(float x){
  return __int_as_float(__builtin_amdgcn_mov_dpp(__float_as_int(x),
                                                 0x138, 0xF, 0xF, true));
}

__device__ __forceinline__ int pk8(float a, float b, float c, float d){
  int v = __builtin_amdgcn_cvt_pk_fp8_f32(a, b, 0, false);
  v = __builtin_amdgcn_cvt_pk_fp8_f32(c, d, v, true);
  return v;
}

// ------------- fused prologue: 4 independent jobs in one dispatch -------------
// r16: e-GEMM section split 256 -> 512 blocks (4 rows x 256 cols each; stage-1
// duplicated at 80 iters, stage-2 per-thread loads halved, 2x blocks/CU for a
// latency-bound L2-streaming loop at previously 4 waves/CU).
// bid 0..511  : e[4 rows x 256 cols] = (inputs @ W_enc) @ W_jenc
// bid 512..641: dmatb(260,512) = emb[padded] @ W_jdec + b_j
// bid 642..673: WTf8 fp8 fragment-order transpose of 32*W_out (2-ks-packed, K=32)
// bid 674..738: zero S[cM]; bid 674 also zeroes out[0] (k_dp atomic target)
__global__ __launch_bounds__(256) void k_pre(
    const float* __restrict__ inputs,
    const float* __restrict__ W_enc, const float* __restrict__ W_jenc,
    const float* __restrict__ emb, const int* __restrict__ targets,
    const float* __restrict__ W_jdec, const float* __restrict__ b_j,
    float* __restrict__ dmatb, float* __restrict__ e,
    const float* __restrict__ W_out, uchar_t* __restrict__ WTf8,
    float* __restrict__ S, float* __restrict__ out_loss)
{
  __shared__ float sA[4][512];
  __shared__ float sIn[4][80];
  int bid = blockIdx.x;
  int tid = threadIdx.x;

  if (bid < 512){
    // ---- e rows m0..m0+3, cols half*256..+255 ----
    int m0 = (bid >> 1) * 4;
    int half = bid & 1;
    // r20 BUG FIX: 320 elements with 256 threads needs a strided loop.
    for (int i = tid; i < 320; i += 256)
      sIn[i / 80][i % 80] = inputs[m0 * 80 + i];
    __syncthreads();
    // stage 1 (full 512 cols; duplicated across the half-blocks, 80 iters)
    int c0 = tid, c1 = tid + 256;
    float a00 = 0.f, a01 = 0.f, a10 = 0.f, a11 = 0.f;
    float a20 = 0.f, a21 = 0.f, a30 = 0.f, a31 = 0.f;
#pragma unroll 8
    for (int k = 0; k < 80; k++){
      float w0 = W_enc[(size_t)k * 512 + c0];
      float w1 = W_enc[(size_t)k * 512 + c1];
      a00 = fmaf(sIn[0][k], w0, a00); a01 = fmaf(sIn[0][k], w1, a01);
      a10 = fmaf(sIn[1][k], w0, a10); a11 = fmaf(sIn[1][k], w1, a11);
      a20 = fmaf(sIn[2][k], w0, a20); a21 = fmaf(sIn[2][k], w1, a21);
      a30 = fmaf(sIn[3][k], w0, a30); a31 = fmaf(sIn[3][k], w1, a31);
    }
    sA[0][c0] = a00; sA[0][c1] = a01;
    sA[1][c0] = a10; sA[1][c1] = a11;
    sA[2][c0] = a20; sA[2][c1] = a21;
    sA[3][c0] = a30; sA[3][c1] = a31;
    __syncthreads();
    // stage 2 (256 cols per block: 1 load + 4 FMA per iter)
    int col = half * 256 + tid;
    float b0 = 0.f, b1 = 0.f, b2 = 0.f, b3 = 0.f;
#pragma unroll 8
    for (int k = 0; k < 512; k++){
      float w = W_jenc[(size_t)k * 512 + col];
      b0 = fmaf(sA[0][k], w, b0);
      b1 = fmaf(sA[1][k], w, b1);
      b2 = fmaf(sA[2][k], w, b2);
      b3 = fmaf(sA[3][k], w, b3);
    }
    e[(size_t)(m0 + 0) * 512 + col] = b0;
    e[(size_t)(m0 + 1) * 512 + col] = b1;
    e[(size_t)(m0 + 2) * 512 + col] = b2;
    e[(size_t)(m0 + 3) * 512 + col] = b3;
  } else if (bid < 642){
    // ---- dmatb = emb[padded] @ W_jdec + b_j ----
    int id = bid - 512;                  // 0..129
    int bx = id & 1, by = id >> 1;
    int m0 = by * 4;
    int col = bx * 256 + tid;
    for (int i = tid; i < 4 * 512; i += 256){
      int r = i >> 9, c = i & 511;
      int row = m0 + r;
      int b = row / cU1, u = row % cU1;
      int src = (u == 0) ? 0 : targets[b * cU + (u - 1)];
      sA[r][c] = emb[(size_t)src * cH + c];
    }
    __syncthreads();
    float a0 = 0.f, a1 = 0.f, a2 = 0.f, a3 = 0.f;
#pragma unroll 8
    for (int k = 0; k < 512; k++){
      float bv = W_jdec[(size_t)k * cJ + col];
      a0 = fmaf(sA[0][k], bv, a0);
      a1 = fmaf(sA[1][k], bv, a1);
      a2 = fmaf(sA[2][k], bv, a2);
      a3 = fmaf(sA[3][k], bv, a3);
    }
    float bb = b_j[col];
    dmatb[(size_t)(m0 + 0) * cJ + col] = a0 + bb;
    dmatb[(size_t)(m0 + 1) * cJ + col] = a1 + bb;
    dmatb[(size_t)(m0 + 2) * cJ + col] = a2 + bb;
    dmatb[(size_t)(m0 + 3) * cJ + col] = a3 + bb;
  } else if (bid < 674){
    // ---- WTf8[((bn4*8+ksp)*16 + nt16)*1024 + lane*16]  (K=32, 2-ks-packed) ----
    int id = bid - 642;                  // 0..31
    int bn = id & 3, ksp = id >> 2;      // ksp 0..7
    int lane = tid & 63, nth = tid >> 6;
    int c16 = lane & 15, quad = lane >> 4;
    int jA = ksp * 64 + quad * 8;
#pragma unroll
    for (int i = 0; i < 4; i++){
      int nt16 = nth * 4 + i;
      int n = bn * 256 + nt16 * 16 + c16;
      unsigned int p[4];
#pragma unroll
      for (int h = 0; h < 4; h++){
        int j0 = jA + (h >> 1) * 32 + (h & 1) * 4;
        float w0 = W_out[(size_t)(j0 + 0) * cV + n] * 32.f;
        float w1 = W_out[(size_t)(j0 + 1) * cV + n] * 32.f;
        float w2 = W_out[(size_t)(j0 + 2) * cV + n] * 32.f;
        float w3 = W_out[(size_t)(j0 + 3) * cV + n] * 32.f;
        p[h] = (unsigned)pk8(w0, w1, w2, w3);
      }
      uint4 pack; pack.x = p[0]; pack.y = p[1]; pack.z = p[2]; pack.w = p[3];
      *(uint4*)(WTf8 + (((size_t)(bn * 8 + ksp) * 16 + nt16) * 64 + lane) * 16) = pack;
    }
  } else {
    // ---- zero S: 65 blocks x 256 thr x 4 floats = 66560 ----
    int i = (bid - 674) * 1024 + tid * 4;
    float4 z; z.x = 0.f; z.y = 0.f; z.z = 0.f; z.w = 0.f;
    *(float4*)(S + i) = z;
    if (bid == 674 && tid == 0) out_loss[0] = 0.f;
  }
}

// ------------- H fp8 fragment-order (K=32), t-minor, coalesced via LDS bounce -------------
// r16: split 520 -> 1040 blocks; each handles 4 of the 8 mg groups (pure range
// split, layout unchanged) -> 4 blocks/CU for better e-load latency hiding.
__global__ __launch_bounds__(256) void k_hf(const float* __restrict__ e,
                                            const float* __restrict__ dmatb,
                                            uchar_t* __restrict__ Hbf8){
  __shared__ uchar_t sH[16 * 520];    // 16 rows x 512 B, pad 8 B
  int tid = threadIdx.x;
  int wid = tid >> 6, lane = tid & 63;
  int c16 = lane & 15, quad = lane >> 4;
  int bm = blockIdx.x >> 1;
  int mgh = blockIdx.x & 1;           // mg half: 0 -> mg 0..3, 1 -> mg 4..7
  int bu = bm >> 1, thalf = bm & 1;
  int b = bu / cU1;
  int t0 = thalf * 128;

  float dj[8];
  const float4* dp = (const float4*)(dmatb + (size_t)bu * cJ + lane * 8);
  float4 dA = dp[0], dB = dp[1];
  dj[0] = dA.x; dj[1] = dA.y; dj[2] = dA.z; dj[3] = dA.w;
  dj[4] = dB.x; dj[5] = dB.y; dj[6] = dB.z; dj[7] = dB.w;

  const float* erow0 = e + ((size_t)(b * cT + t0)) * cJ + lane * 8;
  uchar_t* outb = Hbf8 + (size_t)bm * 65536 + lane * 16;

  for (int mg = mgh * 4; mg < mgh * 4 + 4; mg++){
#pragma unroll
    for (int rr = 0; rr < 4; rr++){
      int rloc = wid * 4 + rr;
      const float* ep = erow0 + ((size_t)(mg * 16 + rloc)) * cJ;
      float4 e0 = *(const float4*)ep;
      float4 e1 = *(const float4*)(ep + 4);
      int v0 = pk8(tanh_fast(e0.x + dj[0]), tanh_fast(e0.y + dj[1]),
                   tanh_fast(e0.z + dj[2]), tanh_fast(e0.w + dj[3]));
      int v1 = pk8(tanh_fast(e1.x + dj[4]), tanh_fast(e1.y + dj[5]),
                   tanh_fast(e1.z + dj[6]), tanh_fast(e1.w + dj[7]));
      uint2 pk; pk.x = (unsigned)v0; pk.y = (unsigned)v1;
      *(uint2*)(sH + rloc * 520 + lane * 8) = pk;
    }
    __syncthreads();
#pragma unroll
    for (int q = 0; q < 2; q++){
      int ksp = wid * 2 + q;
      uint2 lo = *(const uint2*)(sH + c16 * 520 + ksp * 64 + quad * 8);
      uint2 hi = *(const uint2*)(sH + c16 * 520 + ksp * 64 + 32 + quad * 8);
      uint4 pack; pack.x = lo.x; pack.y = lo.y; pack.z = hi.x; pack.w = hi.y;
      *(uint4*)(outb + ((size_t)ksp * 8 + mg) * 1024) = pack;
    }
    __syncthreads();
  }
}

// ------------- joint GEMM fp8 K=32: 64x64 wave tile, LDS-partial epilogue -------------
// r16: REVERT to the measured-52.6us r14 body. r15's 32x32x16 shape regressed
// (73.8us, MfmaUtil 39%): per load group the covering MFMA work fell 160cy ->
// 64cy, so load latency surfaced. 16x16x32 + LDS-partial epilogue stands.
__global__ __launch_bounds__(256, 3) void k_joint(
    const uchar_t* __restrict__ Hbf8, const uchar_t* __restrict__ WTf8,
    const float* __restrict__ b_out, const int* __restrict__ targets,
    float* __restrict__ S,
    float* __restrict__ blank_g, float* __restrict__ lbl_g)
{
  __shared__ float redP[2][128][19];   // 19456 B

  int tid = threadIdx.x;
  int wid = tid >> 6, lane = tid & 63;
  int quad = lane >> 4, c16 = lane & 15;
  int wm = wid & 1, wn = wid >> 1;
  int bid = blockIdx.x;
  int bm = ((bid >> 6) << 3) + (bid & 7);
  int bn = (bid >> 3) & 7;                       // 128-col strip
  int bu = bm >> 1, thalf = bm & 1;
  int b = bu / cU1, u = bu - b * cU1;
  int tg = (u < cU) ? targets[b * cU + u] : -1;
  int lin0 = bu * cT + thalf * 128;              // (b,u,t)-linear base

  f32x4 acc[4][4];
#pragma unroll
  for (int i = 0; i < 4; i++)
#pragma unroll
    for (int j = 0; j < 4; j++)
      acc[i][j] = (f32x4){0.f, 0.f, 0.f, 0.f};

  const uchar_t* aP = Hbf8 + (size_t)bm * 65536 + (wm * 4) * 1024 + lane * 16;
  const uchar_t* bP = WTf8 + (size_t)(bn >> 1) * 131072 + ((bn & 1) * 8 + wn * 4) * 1024 + lane * 16;

  v2i64 afX[4], bfX[4], afY[4], bfY[4];
#pragma unroll
  for (int mt = 0; mt < 4; mt++) afX[mt] = *(const v2i64*)(aP + mt * 1024);
#pragma unroll
  for (int nt = 0; nt < 4; nt++) bfX[nt] = *(const v2i64*)(bP + nt * 1024);

#pragma unroll
  for (int k2 = 0; k2 < 4; k2++){
    // ---- issue loads for ksp = 2*k2+1 (Y) a full MFMA stage early ----
    {
      size_t kY = (size_t)(2 * k2 + 1);
#pragma unroll
      for (int mt = 0; mt < 4; mt++) afY[mt] = *(const v2i64*)(aP + kY * 8192 + mt * 1024);
#pragma unroll
      for (int nt = 0; nt < 4; nt++) bfY[nt] = *(const v2i64*)(bP + kY * 16384 + nt * 1024);
    }
    // ---- MFMA on X (covers Y's load latency) ----
#pragma unroll
    for (int h = 0; h < 2; h++)
#pragma unroll
      for (int mt = 0; mt < 4; mt++)
#pragma unroll
        for (int nt = 0; nt < 4; nt++)
          acc[mt][nt] = __builtin_amdgcn_mfma_f32_16x16x32_fp8_fp8(afX[mt][h], bfX[nt][h], acc[mt][nt], 0, 0, 0);
    // ---- issue loads for ksp = 2*k2+2 (X), statically guarded ----
    if (k2 < 3){
      size_t kX = (size_t)(2 * k2 + 2);
#pragma unroll
      for (int mt = 0; mt < 4; mt++) afX[mt] = *(const v2i64*)(aP + kX * 8192 + mt * 1024);
#pragma unroll
      for (int nt = 0; nt < 4; nt++) bfX[nt] = *(const v2i64*)(bP + kX * 16384 + nt * 1024);
    }
    // ---- MFMA on Y (covers X's load latency) ----
#pragma unroll
    for (int h = 0; h < 2; h++)
#pragma unroll
      for (int mt = 0; mt < 4; mt++)
#pragma unroll
        for (int nt = 0; nt < 4; nt++)
          acc[mt][nt] = __builtin_amdgcn_mfma_f32_16x16x32_fp8_fp8(afY[mt][h], bfY[nt][h], acc[mt][nt], 0, 0, 0);
  }

  float bv[4];
#pragma unroll
  for (int nt = 0; nt < 4; nt++) bv[nt] = b_out[bn * 128 + (wn * 4 + nt) * 16 + c16] * LOG2E;

  bool ownL = (tg >= 0) && ((tg >> 7) == bn) && (((tg >> 6) & 1) == wn);
  int ntO = (tg >> 4) & 3;
  int tgc = tg & 15;
  const float descale2 = LOG2E / 32.f;  // undo *32 on W_out fp8 AND go log2-domain

#pragma unroll
  for (int mt = 0; mt < 4; mt++){
#pragma unroll
    for (int r = 0; r < 4; r++){
      int rl = wm * 64 + mt * 16 + quad * 4 + r;  // C/D: col=lane&15, row=quad*4+reg (m89)
      float l[4];
#pragma unroll
      for (int nt = 0; nt < 4; nt++) l[nt] = fmaf(acc[mt][nt][r], descale2, bv[nt]);
      if (bn == 0 && wn == 0 && c16 == 0) blank_g[lin0 + rl] = l[0];
      if (ownL && c16 == tgc){
        float v = l[0];
#pragma unroll
        for (int k = 1; k < 4; k++) v = (ntO == k) ? l[k] : v;
        lbl_g[lin0 + rl] = v;
      }
      redP[wn][rl][c16] = __builtin_amdgcn_exp2f(l[0]) + __builtin_amdgcn_exp2f(l[1])
                        + __builtin_amdgcn_exp2f(l[2]) + __builtin_amdgcn_exp2f(l[3]);
    }
  }
  __syncthreads();
  if (tid < 128){
    float a = 0.f;
#pragma unroll
    for (int j = 0; j < 16; j++) a += redP[0][tid][j] + redP[1][tid][j];
    atomicAdd(&S[lin0 + tid], a);
  }
}

// ------------- RNN-T alpha DP: phase-split producer/consumer + gmax truncation -------------
// (unchanged from the measured-202.9us r14 version)
__global__ __launch_bounds__(256) void k_dp(
    const float* __restrict__ S, const float* __restrict__ blank_g,
    const float* __restrict__ lbl_g,
    const int* __restrict__ in_len, const int* __restrict__ tgt_len,
    float* __restrict__ out)
{
  constexpr int G = 16;        // g-steps per chunk
  __shared__ float sbb[cTU];   // 65 KB, (u,t): index u*256+t  (log2 domain)
  __shared__ float slb[cTU];   // 65 KB
  __shared__ float sS[256];    // alpha[t][63] history (lane 63)
  __shared__ float cC0[G * 64], cC1[G * 64], cC2[G * 64];
  __shared__ float cOA[G * 64], cOB[G * 64];
  int tid = threadIdx.x;
  int b = blockIdx.x;
  int tl  = tgt_len[b];                // 32..64
  size_t base = (size_t)b * cTU;
  for (int i = tid; i < cTU / 4; i += 256){
    int row = i >> 6;                  // float4 never crosses a 256-elem row
    if (row > tl) continue;            // rows > tl unread by any live lane
    float4 sv = ((const float4*)(S + base))[i];
    float4 bvv = ((const float4*)(blank_g + base))[i];
    float4 ls;
    ls.x = __builtin_amdgcn_logf(sv.x); ls.y = __builtin_amdgcn_logf(sv.y);
    ls.z = __builtin_amdgcn_logf(sv.z); ls.w = __builtin_amdgcn_logf(sv.w);
    float4 bo;
    bo.x = bvv.x - ls.x; bo.y = bvv.y - ls.y;
    bo.z = bvv.z - ls.z; bo.w = bvv.w - ls.w;
    ((float4*)sbb)[i] = bo;
    float4 lo;
    if (row < tl){
      float4 lv = ((const float4*)(lbl_g + base))[i];
      lo.x = lv.x - ls.x; lo.y = lv.y - ls.y;
      lo.z = lv.z - ls.z; lo.w = lv.w - ls.w;
    } else {
      lo.x = NEGF; lo.y = NEGF; lo.z = NEGF; lo.w = NEGF;
    }
    ((float4*)slb)[i] = lo;
  }
  __syncthreads();

  int til = in_len[b] - 1;
  bool cap64 = (tl == 64);
  int u = tid;                         // meaningful for tid<64
  bool isTL = (u == tl);
  float fb = (tid < 64) ? sbb[(u << 8) + til] : 0.f;

  // last diagonal needed: res captures at g<=ceil((til+tl)/2); sS fills
  // (cap64 path) need g<=ceil((til+62)/2). +2 safety; cap at 159.
  int need = til + tl;
  if (cap64 && til + 62 > need) need = til + 62;
  int gmax = (need >> 1) + 2;
  if (gmax > 159) gmax = 159;
  int nph = (gmax + G - 1) / G;        // block-uniform

  float A = (u == 0) ? 0.f : NEGF;     // alpha on even diagonal d = 2g (log2)
  float res = 0.f;

  auto ld = [&](const float* p, int i, bool ok) -> float {
    float x = p[i & 255];              // wrap stays inside sbb/slb
    return (ok & ((unsigned)i < 256u)) ? x : NEGF;
  };

  for (int p = 0; p < nph; p++){
    // ---- fill phase: all 256 threads precompute C/o arrays for this chunk ----
    for (int w = tid; w < G * 64; w += 256){
      int gg = w >> 6, uu = w & 63;
      int g = p * G + gg;              // g>=gmax entries filled but never read
      int i0 = 2 * g - uu;
      bool v1 = (uu >= 1), v2 = (uu >= 2);
      const float* pbu  = sbb + (uu << 8);
      const float* pbu1 = sbb + ((v1 ? uu - 1 : 0) << 8);
      const float* plu1 = slb + ((v1 ? uu - 1 : 0) << 8);
      const float* plu2 = slb + ((v2 ? uu - 2 : 0) << 8);
      float o0 = ld(pbu,  i0,     true);   // bb[t-2][u]
      float o1 = ld(pbu,  i0 + 1, true);   // bb[t-1][u]
      float o2 = ld(plu1, i0 + 1, v1);     // lb[t-1][u-1]
      float o3 = ld(pbu1, i0 + 1, v1);     // bb[t-1][u-1]
      float o4 = ld(plu1, i0 + 2, v1);     // lb[t][u-1]
      float o5 = ld(plu2, i0 + 2, v2);     // lb[t][u-2]
      cC0[w] = o0 + o1;
      cC1[w] = logadd2(o2 + o1, o3 + o4);
      cC2[w] = o5 + o4;
      cOA[w] = o0;
      cOB[w] = o2;
    }
    __syncthreads();
    // ---- consume phase: wave 0 runs G recurrence steps ----
    if (tid < 64){
      float c0v = cC0[u], c1v = cC1[u], c2v = cC2[u];
      float oAv = cOA[u], oBv = cOB[u];
#pragma unroll
      for (int gg = 0; gg < G; gg++){
        int g = p * G + gg;
        int nx = (gg + 1 < G) ? ((gg + 1) << 6) + u : (gg << 6) + u;
        float nc0 = cC0[nx], nc1 = cC1[nx], nc2 = cC2[nx];
        float noA = cOA[nx], noB = cOB[nx];
        if (g < gmax){
          float up1 = wshr1(A);
          float up2 = wshr1(up1);
          int i0 = 2 * g - u;
          float Amid = logadd2(A + oAv, up1 + oBv);
          bool tv1 = ((unsigned)(i0 + 1) < 256u);
          Amid = tv1 ? Amid : NEGF;
          float a0 = A + c0v, a1 = up1 + c1v, a2 = up2 + c2v;
          float m3 = fmaxf(fmaxf(a0, a1), a2);          // v_max3
          float s3 = __builtin_amdgcn_exp2f(a0 - m3) + __builtin_amdgcn_exp2f(a1 - m3)
                   + __builtin_amdgcn_exp2f(a2 - m3);
          float Anew = m3 + __builtin_amdgcn_logf(s3);
          bool tv2 = ((unsigned)(i0 + 2) < 256u);
          Anew = tv2 ? Anew : NEGF;
          if (isTL && (i0 + 1) == til) res = Amid + fb;
          if (isTL && (i0 + 2) == til) res = Anew + fb;
          if (u == 63){
            if (tv1) sS[i0 + 1] = Amid;
            if (tv2) sS[i0 + 2] = Anew;
          }
          A = Anew;
        }
        c0v = nc0; c1v = nc1; c2v = nc2; oAv = noA; oBv = noB;
      }
    }
    __syncthreads();                   // protect cArr from next fill
  }

  if (tid >= 64) return;

  if (cap64){
    const float* pb64 = sbb + (64 << 8);
    const float* pl63 = slb + (63 << 8);
    float A64 = sS[0] + pl63[0];       // alpha[0][64]
    for (int t = 1; t <= til; t++)
      A64 = logadd2(A64 + pb64[t - 1], sS[t] + pl63[t]);
    if (u == 0) res = A64 + pb64[til];
  }

  // butterfly-sum broadcasts the single captured value (others hold 0)
  res += __shfl_xor(res, 1, 64);
  res += __shfl_xor(res, 2, 64);
  res += __shfl_xor(res, 4, 64);
  res += __shfl_xor(res, 8, 64);
  res += __shfl_xor(res, 16, 64);
  res += __shfl_xor(res, 32, 64);
  if (u == 0) atomicAdd(out, -0.17328679513998632f * res);  // -0.25 * ln2 (log2->ln)
}

extern "C" void kernel_launch(void* const* d_in, const int* in_sizes, int n_in,
                              void* d_out, int out_size, void* d_ws, size_t ws_size,
                              hipStream_t stream)
{
  (void)in_sizes; (void)n_in; (void)out_size; (void)ws_size;
  const float* inputs = (const float*)d_in[0];   // (4,256,80)
  const float* W_enc  = (const float*)d_in[1];   // (80,512)
  const float* emb    = (const float*)d_in[2];   // (1024,512)
  const float* W_jenc = (const float*)d_in[3];   // (512,512)
  const float* W_jdec = (const float*)d_in[4];   // (512,512)
  const float* b_j    = (const float*)d_in[5];   // (512)
  const float* W_out  = (const float*)d_in[6];   // (512,1024)
  const float* b_out  = (const float*)d_in[7];   // (1024)
  const int* targets  = (const int*)d_in[8];     // (4,64)
  const int* in_len   = (const int*)d_in[9];     // (4)
  const int* tgt_len  = (const int*)d_in[10];    // (4)

  char* w = (char*)d_ws;
  auto alloc = [&](size_t bytes){ char* p = w; w += (bytes + 255) & ~(size_t)255; return p; };
  float* e       = (float*)alloc((size_t)1024 * 512 * 4);
  float* dmatb   = (float*)alloc((size_t)260 * 512 * 4);
  float* blank_g = (float*)alloc((size_t)cM * 4);
  float* lbl_g   = (float*)alloc((size_t)cM * 4);
  float* S       = (float*)alloc((size_t)cM * 4);
  uchar_t* Hbf8  = (uchar_t*)alloc((size_t)520 * 65536);
  uchar_t* WTf8  = (uchar_t*)alloc((size_t)4 * 131072);

  k_pre<<<739, 256, 0, stream>>>(inputs, W_enc, W_jenc, emb, targets, W_jdec, b_j,
                                 dmatb, e, W_out, WTf8, S, (float*)d_out);
  k_hf<<<1040, 256, 0, stream>>>(e, dmatb, Hbf8);
  k_joint<<<4160, 256, 0, stream>>>(Hbf8, WTf8, b_out, targets, S, blank_g, lbl_g);
  k_dp<<<4, 256, 0, stream>>>(S, blank_g, lbl_g, in_len, tgt_len, (float*)d_out);
}

// Round 17
// 201.561 us; speedup vs baseline: 1.1033x; 1.0025x over previous
//
#include <hip/hip_runtime.h>
#include <stdint.h>

#define NEGF (-1e30f)

typedef unsigned short ushort_t;
typedef unsigned char uchar_t;
typedef __attribute__((ext_vector_type(2))) long v2i64;
typedef __attribute__((ext_vector_type(4))) float f32x4;

constexpr int cB = 4, cT = 256, cU = 64, cU1 = 65, cV = 1024, cF = 80, cH = 512, cJ = 512;
constexpr int cM = cB * cT * cU1; // 66560
constexpr int cTU = cT * cU1;     // 16640 (per-batch (u,t) plane: u*256+t)
constexpr float LOG2E = 1.4426950408889634f;

// Padé(2,2) tanh + clamp: max err ~0.016, far below fp8-e4m3 half-step; no v_exp.
__device__ __forceinline__ float tanh_fast(float x){
  float t = x * x;
  float num = x * (27.f + t);
  float den = fmaf(9.f, t, 27.f);
  float r = num * __builtin_amdgcn_rcpf(den);
  return fminf(1.f, fmaxf(-1.f, r));
}

// log2-domain logadd: v_exp_f32/v_log_f32 ARE base-2 -> no ln2 scaling muls.
__device__ __forceinline__ float logadd2(float x, float y){
  float m = fmaxf(x, y);
  return m + __builtin_amdgcn_logf(1.f + __builtin_amdgcn_exp2f(-fabsf(x - y)));
}

// wave shift-right-by-1 via DPP (lane i <- lane i-1); invalid lane 0 reads 0.0f
// (bound_ctrl:0). 2-cycle VALU op on k_dp's serial A->A critical path.
__device__ __forceinline__ float wshr1(float x){
  return __int_as_float(__builtin_amdgcn_mov_dpp(__float_as_int(x),
                                                 0x138, 0xF, 0xF, true));
}

__device__ __forceinline__ int pk8(float a, float b, float c, float d){
  int v = __builtin_amdgcn_cvt_pk_fp8_f32(a, b, 0, false);
  v = __builtin_amdgcn_cvt_pk_fp8_f32(c, d, v, true);
  return v;
}

// ------------- fused prologue: 4 independent jobs in one dispatch -------------
// bid 0..511  : e[4 rows x 256 cols] = (inputs @ W_enc) @ W_jenc
// bid 512..641: dmatb(260,512) = emb[padded] @ W_jdec + b_j
// bid 642..673: WTf8 fp8 fragment-order transpose of 32*W_out (2-ks-packed, K=32)
// bid 674..738: zero S[cM]; bid 674 also zeroes out[0] (k_dp atomic target)
__global__ __launch_bounds__(256) void k_pre(
    const float* __restrict__ inputs,
    const float* __restrict__ W_enc, const float* __restrict__ W_jenc,
    const float* __restrict__ emb, const int* __restrict__ targets,
    const float* __restrict__ W_jdec, const float* __restrict__ b_j,
    float* __restrict__ dmatb, float* __restrict__ e,
    const float* __restrict__ W_out, uchar_t* __restrict__ WTf8,
    float* __restrict__ S, float* __restrict__ out_loss)
{
  __shared__ float sA[4][512];
  __shared__ float sIn[4][80];
  int bid = blockIdx.x;
  int tid = threadIdx.x;

  if (bid < 512){
    // ---- e rows m0..m0+3, cols half*256..+255 ----
    int m0 = (bid >> 1) * 4;
    int half = bid & 1;
    for (int i = tid; i < 320; i += 256)
      sIn[i / 80][i % 80] = inputs[m0 * 80 + i];
    __syncthreads();
    int c0 = tid, c1 = tid + 256;
    float a00 = 0.f, a01 = 0.f, a10 = 0.f, a11 = 0.f;
    float a20 = 0.f, a21 = 0.f, a30 = 0.f, a31 = 0.f;
#pragma unroll 8
    for (int k = 0; k < 80; k++){
      float w0 = W_enc[(size_t)k * 512 + c0];
      float w1 = W_enc[(size_t)k * 512 + c1];
      a00 = fmaf(sIn[0][k], w0, a00); a01 = fmaf(sIn[0][k], w1, a01);
      a10 = fmaf(sIn[1][k], w0, a10); a11 = fmaf(sIn[1][k], w1, a11);
      a20 = fmaf(sIn[2][k], w0, a20); a21 = fmaf(sIn[2][k], w1, a21);
      a30 = fmaf(sIn[3][k], w0, a30); a31 = fmaf(sIn[3][k], w1, a31);
    }
    sA[0][c0] = a00; sA[0][c1] = a01;
    sA[1][c0] = a10; sA[1][c1] = a11;
    sA[2][c0] = a20; sA[2][c1] = a21;
    sA[3][c0] = a30; sA[3][c1] = a31;
    __syncthreads();
    int col = half * 256 + tid;
    float b0 = 0.f, b1 = 0.f, b2 = 0.f, b3 = 0.f;
#pragma unroll 8
    for (int k = 0; k < 512; k++){
      float w = W_jenc[(size_t)k * 512 + col];
      b0 = fmaf(sA[0][k], w, b0);
      b1 = fmaf(sA[1][k], w, b1);
      b2 = fmaf(sA[2][k], w, b2);
      b3 = fmaf(sA[3][k], w, b3);
    }
    e[(size_t)(m0 + 0) * 512 + col] = b0;
    e[(size_t)(m0 + 1) * 512 + col] = b1;
    e[(size_t)(m0 + 2) * 512 + col] = b2;
    e[(size_t)(m0 + 3) * 512 + col] = b3;
  } else if (bid < 642){
    // ---- dmatb = emb[padded] @ W_jdec + b_j ----
    int id = bid - 512;                  // 0..129
    int bx = id & 1, by = id >> 1;
    int m0 = by * 4;
    int col = bx * 256 + tid;
    for (int i = tid; i < 4 * 512; i += 256){
      int r = i >> 9, c = i & 511;
      int row = m0 + r;
      int b = row / cU1, u = row % cU1;
      int src = (u == 0) ? 0 : targets[b * cU + (u - 1)];
      sA[r][c] = emb[(size_t)src * cH + c];
    }
    __syncthreads();
    float a0 = 0.f, a1 = 0.f, a2 = 0.f, a3 = 0.f;
#pragma unroll 8
    for (int k = 0; k < 512; k++){
      float bv = W_jdec[(size_t)k * cJ + col];
      a0 = fmaf(sA[0][k], bv, a0);
      a1 = fmaf(sA[1][k], bv, a1);
      a2 = fmaf(sA[2][k], bv, a2);
      a3 = fmaf(sA[3][k], bv, a3);
    }
    float bb = b_j[col];
    dmatb[(size_t)(m0 + 0) * cJ + col] = a0 + bb;
    dmatb[(size_t)(m0 + 1) * cJ + col] = a1 + bb;
    dmatb[(size_t)(m0 + 2) * cJ + col] = a2 + bb;
    dmatb[(size_t)(m0 + 3) * cJ + col] = a3 + bb;
  } else if (bid < 674){
    // ---- WTf8[((bn4*8+ksp)*16 + nt16)*1024 + lane*16]  (K=32, 2-ks-packed) ----
    int id = bid - 642;                  // 0..31
    int bn = id & 3, ksp = id >> 2;      // ksp 0..7
    int lane = tid & 63, nth = tid >> 6;
    int c16 = lane & 15, quad = lane >> 4;
    int jA = ksp * 64 + quad * 8;
#pragma unroll
    for (int i = 0; i < 4; i++){
      int nt16 = nth * 4 + i;
      int n = bn * 256 + nt16 * 16 + c16;
      unsigned int p[4];
#pragma unroll
      for (int h = 0; h < 4; h++){
        int j0 = jA + (h >> 1) * 32 + (h & 1) * 4;
        float w0 = W_out[(size_t)(j0 + 0) * cV + n] * 32.f;
        float w1 = W_out[(size_t)(j0 + 1) * cV + n] * 32.f;
        float w2 = W_out[(size_t)(j0 + 2) * cV + n] * 32.f;
        float w3 = W_out[(size_t)(j0 + 3) * cV + n] * 32.f;
        p[h] = (unsigned)pk8(w0, w1, w2, w3);
      }
      uint4 pack; pack.x = p[0]; pack.y = p[1]; pack.z = p[2]; pack.w = p[3];
      *(uint4*)(WTf8 + (((size_t)(bn * 8 + ksp) * 16 + nt16) * 64 + lane) * 16) = pack;
    }
  } else {
    // ---- zero S: 65 blocks x 256 thr x 4 floats = 66560 ----
    int i = (bid - 674) * 1024 + tid * 4;
    float4 z; z.x = 0.f; z.y = 0.f; z.z = 0.f; z.w = 0.f;
    *(float4*)(S + i) = z;
    if (bid == 674 && tid == 0) out_loss[0] = 0.f;
  }
}

// ------------- H fp8 fragment-order (K=32), t-minor, coalesced via LDS bounce -------------
__global__ __launch_bounds__(256) void k_hf(const float* __restrict__ e,
                                            const float* __restrict__ dmatb,
                                            uchar_t* __restrict__ Hbf8){
  __shared__ uchar_t sH[16 * 520];    // 16 rows x 512 B, pad 8 B
  int tid = threadIdx.x;
  int wid = tid >> 6, lane = tid & 63;
  int c16 = lane & 15, quad = lane >> 4;
  int bm = blockIdx.x >> 1;
  int mgh = blockIdx.x & 1;           // mg half: 0 -> mg 0..3, 1 -> mg 4..7
  int bu = bm >> 1, thalf = bm & 1;
  int b = bu / cU1;
  int t0 = thalf * 128;

  float dj[8];
  const float4* dp = (const float4*)(dmatb + (size_t)bu * cJ + lane * 8);
  float4 dA = dp[0], dB = dp[1];
  dj[0] = dA.x; dj[1] = dA.y; dj[2] = dA.z; dj[3] = dA.w;
  dj[4] = dB.x; dj[5] = dB.y; dj[6] = dB.z; dj[7] = dB.w;

  const float* erow0 = e + ((size_t)(b * cT + t0)) * cJ + lane * 8;
  uchar_t* outb = Hbf8 + (size_t)bm * 65536 + lane * 16;

  for (int mg = mgh * 4; mg < mgh * 4 + 4; mg++){
#pragma unroll
    for (int rr = 0; rr < 4; rr++){
      int rloc = wid * 4 + rr;
      const float* ep = erow0 + ((size_t)(mg * 16 + rloc)) * cJ;
      float4 e0 = *(const float4*)ep;
      float4 e1 = *(const float4*)(ep + 4);
      int v0 = pk8(tanh_fast(e0.x + dj[0]), tanh_fast(e0.y + dj[1]),
                   tanh_fast(e0.z + dj[2]), tanh_fast(e0.w + dj[3]));
      int v1 = pk8(tanh_fast(e1.x + dj[4]), tanh_fast(e1.y + dj[5]),
                   tanh_fast(e1.z + dj[6]), tanh_fast(e1.w + dj[7]));
      uint2 pk; pk.x = (unsigned)v0; pk.y = (unsigned)v1;
      *(uint2*)(sH + rloc * 520 + lane * 8) = pk;
    }
    __syncthreads();
#pragma unroll
    for (int q = 0; q < 2; q++){
      int ksp = wid * 2 + q;
      uint2 lo = *(const uint2*)(sH + c16 * 520 + ksp * 64 + quad * 8);
      uint2 hi = *(const uint2*)(sH + c16 * 520 + ksp * 64 + 32 + quad * 8);
      uint4 pack; pack.x = lo.x; pack.y = lo.y; pack.z = hi.x; pack.w = hi.y;
      *(uint4*)(outb + ((size_t)ksp * 8 + mg) * 1024) = pack;
    }
    __syncthreads();
  }
}

// ------------- joint GEMM fp8 K=32: asm counted-vmcnt 2-deep pipeline -------------
// r17: the compiler re-serialized every source-level pipeline (r6: one frag
// set live, vmcnt(0) drain per stage -> load latency exposed, MfmaUtil 52%).
// Guide T4: counted s_waitcnt vmcnt(N) via inline asm is the documented
// escape. Stages k,k+1 in flight (16 loads); per stage: vmcnt(8) waits ONLY
// for the oldest 8 (this stage's operands), sched_barrier(0) fences MFMA
// hoisting (rule #18), MFMA, then issue stage k+2 (back to 16 in flight).
// targets/b_out loads moved AFTER the pipeline so the vmcnt FIFO holds only
// counted loads. Tripwire: WRITE_SIZE must stay ~2.6MB.
#define LDSET(av, bw, s) do { \
    const uchar_t* _a = aP + (size_t)(s) * 8192; \
    const uchar_t* _b = bP + (size_t)(s) * 16384; \
    asm volatile("global_load_dwordx4 %0, %1, off"             : "=v"(av[0]) : "v"(_a)); \
    asm volatile("global_load_dwordx4 %0, %1, off offset:1024" : "=v"(av[1]) : "v"(_a)); \
    asm volatile("global_load_dwordx4 %0, %1, off offset:2048" : "=v"(av[2]) : "v"(_a)); \
    asm volatile("global_load_dwordx4 %0, %1, off offset:3072" : "=v"(av[3]) : "v"(_a)); \
    asm volatile("global_load_dwordx4 %0, %1, off"             : "=v"(bw[0]) : "v"(_b)); \
    asm volatile("global_load_dwordx4 %0, %1, off offset:1024" : "=v"(bw[1]) : "v"(_b)); \
    asm volatile("global_load_dwordx4 %0, %1, off offset:2048" : "=v"(bw[2]) : "v"(_b)); \
    asm volatile("global_load_dwordx4 %0, %1, off offset:3072" : "=v"(bw[3]) : "v"(_b)); \
  } while (0)

#define WV8 do { asm volatile("s_waitcnt vmcnt(8)" ::: "memory"); \
                 __builtin_amdgcn_sched_barrier(0); } while (0)
#define WV0 do { asm volatile("s_waitcnt vmcnt(0)" ::: "memory"); \
                 __builtin_amdgcn_sched_barrier(0); } while (0)

#define MFSET(av, bw) do { \
    _Pragma("unroll") \
    for (int h = 0; h < 2; h++) \
      _Pragma("unroll") \
      for (int mt = 0; mt < 4; mt++) \
        _Pragma("unroll") \
        for (int nt = 0; nt < 4; nt++) \
          acc[mt][nt] = __builtin_amdgcn_mfma_f32_16x16x32_fp8_fp8(av[mt][h], bw[nt][h], acc[mt][nt], 0, 0, 0); \
  } while (0)

__global__ __launch_bounds__(256, 3) void k_joint(
    const uchar_t* __restrict__ Hbf8, const uchar_t* __restrict__ WTf8,
    const float* __restrict__ b_out, const int* __restrict__ targets,
    float* __restrict__ S,
    float* __restrict__ blank_g, float* __restrict__ lbl_g)
{
  __shared__ float redP[2][128][19];   // 19456 B

  int tid = threadIdx.x;
  int wid = tid >> 6, lane = tid & 63;
  int quad = lane >> 4, c16 = lane & 15;
  int wm = wid & 1, wn = wid >> 1;
  int bid = blockIdx.x;
  int bm = ((bid >> 6) << 3) + (bid & 7);
  int bn = (bid >> 3) & 7;                       // 128-col strip
  int bu = bm >> 1, thalf = bm & 1;
  int b = bu / cU1, u = bu - b * cU1;
  int lin0 = bu * cT + thalf * 128;              // (b,u,t)-linear base

  f32x4 acc[4][4];
#pragma unroll
  for (int i = 0; i < 4; i++)
#pragma unroll
    for (int j = 0; j < 4; j++)
      acc[i][j] = (f32x4){0.f, 0.f, 0.f, 0.f};

  const uchar_t* aP = Hbf8 + (size_t)bm * 65536 + (wm * 4) * 1024 + lane * 16;
  const uchar_t* bP = WTf8 + (size_t)(bn >> 1) * 131072 + ((bn & 1) * 8 + wn * 4) * 1024 + lane * 16;

  v2i64 afX[4], bfX[4], afY[4], bfY[4];

  LDSET(afX, bfX, 0);        // in flight: 8
  LDSET(afY, bfY, 1);        // in flight: 16
  WV8;  MFSET(afX, bfX);  LDSET(afX, bfX, 2);   // wait st0, compute, refill
  WV8;  MFSET(afY, bfY);  LDSET(afY, bfY, 3);
  WV8;  MFSET(afX, bfX);  LDSET(afX, bfX, 4);
  WV8;  MFSET(afY, bfY);  LDSET(afY, bfY, 5);
  WV8;  MFSET(afX, bfX);  LDSET(afX, bfX, 6);
  WV8;  MFSET(afY, bfY);  LDSET(afY, bfY, 7);
  WV8;  MFSET(afX, bfX);
  WV0;  MFSET(afY, bfY);

  // epilogue-only loads (kept out of the counted vmcnt window)
  int tg = (u < cU) ? targets[b * cU + u] : -1;
  float bv[4];
#pragma unroll
  for (int nt = 0; nt < 4; nt++) bv[nt] = b_out[bn * 128 + (wn * 4 + nt) * 16 + c16] * LOG2E;

  bool ownL = (tg >= 0) && ((tg >> 7) == bn) && (((tg >> 6) & 1) == wn);
  int ntO = (tg >> 4) & 3;
  int tgc = tg & 15;
  const float descale2 = LOG2E / 32.f;  // undo *32 on W_out fp8 AND go log2-domain

#pragma unroll
  for (int mt = 0; mt < 4; mt++){
#pragma unroll
    for (int r = 0; r < 4; r++){
      int rl = wm * 64 + mt * 16 + quad * 4 + r;  // C/D: col=lane&15, row=quad*4+reg (m89)
      float l[4];
#pragma unroll
      for (int nt = 0; nt < 4; nt++) l[nt] = fmaf(acc[mt][nt][r], descale2, bv[nt]);
      if (bn == 0 && wn == 0 && c16 == 0) blank_g[lin0 + rl] = l[0];
      if (ownL && c16 == tgc){
        float v = l[0];
#pragma unroll
        for (int k = 1; k < 4; k++) v = (ntO == k) ? l[k] : v;
        lbl_g[lin0 + rl] = v;
      }
      redP[wn][rl][c16] = __builtin_amdgcn_exp2f(l[0]) + __builtin_amdgcn_exp2f(l[1])
                        + __builtin_amdgcn_exp2f(l[2]) + __builtin_amdgcn_exp2f(l[3]);
    }
  }
  __syncthreads();
  if (tid < 128){
    float a = 0.f;
#pragma unroll
    for (int j = 0; j < 16; j++) a += redP[0][tid][j] + redP[1][tid][j];
    atomicAdd(&S[lin0 + tid], a);
  }
}

// ------------- RNN-T alpha DP: phase-split producer/consumer + gmax truncation -------------
// (unchanged from the measured-202.1us r16 version)
__global__ __launch_bounds__(256) void k_dp(
    const float* __restrict__ S, const float* __restrict__ blank_g,
    const float* __restrict__ lbl_g,
    const int* __restrict__ in_len, const int* __restrict__ tgt_len,
    float* __restrict__ out)
{
  constexpr int G = 16;        // g-steps per chunk
  __shared__ float sbb[cTU];   // 65 KB, (u,t): index u*256+t  (log2 domain)
  __shared__ float slb[cTU];   // 65 KB
  __shared__ float sS[256];    // alpha[t][63] history (lane 63)
  __shared__ float cC0[G * 64], cC1[G * 64], cC2[G * 64];
  __shared__ float cOA[G * 64], cOB[G * 64];
  int tid = threadIdx.x;
  int b = blockIdx.x;
  int tl  = tgt_len[b];                // 32..64
  size_t base = (size_t)b * cTU;
  for (int i = tid; i < cTU / 4; i += 256){
    int row = i >> 6;                  // float4 never crosses a 256-elem row
    if (row > tl) continue;            // rows > tl unread by any live lane
    float4 sv = ((const float4*)(S + base))[i];
    float4 bvv = ((const float4*)(blank_g + base))[i];
    float4 ls;
    ls.x = __builtin_amdgcn_logf(sv.x); ls.y = __builtin_amdgcn_logf(sv.y);
    ls.z = __builtin_amdgcn_logf(sv.z); ls.w = __builtin_amdgcn_logf(sv.w);
    float4 bo;
    bo.x = bvv.x - ls.x; bo.y = bvv.y - ls.y;
    bo.z = bvv.z - ls.z; bo.w = bvv.w - ls.w;
    ((float4*)sbb)[i] = bo;
    float4 lo;
    if (row < tl){
      float4 lv = ((const float4*)(lbl_g + base))[i];
      lo.x = lv.x - ls.x; lo.y = lv.y - ls.y;
      lo.z = lv.z - ls.z; lo.w = lv.w - ls.w;
    } else {
      lo.x = NEGF; lo.y = NEGF; lo.z = NEGF; lo.w = NEGF;
    }
    ((float4*)slb)[i] = lo;
  }
  __syncthreads();

  int til = in_len[b] - 1;
  bool cap64 = (tl == 64);
  int u = tid;                         // meaningful for tid<64
  bool isTL = (u == tl);
  float fb = (tid < 64) ? sbb[(u << 8) + til] : 0.f;

  // last diagonal needed: res captures at g<=ceil((til+tl)/2); sS fills
  // (cap64 path) need g<=ceil((til+62)/2). +2 safety; cap at 159.
  int need = til + tl;
  if (cap64 && til + 62 > need) need = til + 62;
  int gmax = (need >> 1) + 2;
  if (gmax > 159) gmax = 159;
  int nph = (gmax + G - 1) / G;        // block-uniform

  float A = (u == 0) ? 0.f : NEGF;     // alpha on even diagonal d = 2g (log2)
  float res = 0.f;

  auto ld = [&](const float* p, int i, bool ok) -> float {
    float x = p[i & 255];              // wrap stays inside sbb/slb
    return (ok & ((unsigned)i < 256u)) ? x : NEGF;
  };

  for (int p = 0; p < nph; p++){
    // ---- fill phase: all 256 threads precompute C/o arrays for this chunk ----
    for (int w = tid; w < G * 64; w += 256){
      int gg = w >> 6, uu = w & 63;
      int g = p * G + gg;              // g>=gmax entries filled but never read
      int i0 = 2 * g - uu;
      bool v1 = (uu >= 1), v2 = (uu >= 2);
      const float* pbu  = sbb + (uu << 8);
      const float* pbu1 = sbb + ((v1 ? uu - 1 : 0) << 8);
      const float* plu1 = slb + ((v1 ? uu - 1 : 0) << 8);
      const float* plu2 = slb + ((v2 ? uu - 2 : 0) << 8);
      float o0 = ld(pbu,  i0,     true);   // bb[t-2][u]
      float o1 = ld(pbu,  i0 + 1, true);   // bb[t-1][u]
      float o2 = ld(plu1, i0 + 1, v1);     // lb[t-1][u-1]
      float o3 = ld(pbu1, i0 + 1, v1);     // bb[t-1][u-1]
      float o4 = ld(plu1, i0 + 2, v1);     // lb[t][u-1]
      float o5 = ld(plu2, i0 + 2, v2);     // lb[t][u-2]
      cC0[w] = o0 + o1;
      cC1[w] = logadd2(o2 + o1, o3 + o4);
      cC2[w] = o5 + o4;
      cOA[w] = o0;
      cOB[w] = o2;
    }
    __syncthreads();
    // ---- consume phase: wave 0 runs G recurrence steps ----
    if (tid < 64){
      float c0v = cC0[u], c1v = cC1[u], c2v = cC2[u];
      float oAv = cOA[u], oBv = cOB[u];
#pragma unroll
      for (int gg = 0; gg < G; gg++){
        int g = p * G + gg;
        int nx = (gg + 1 < G) ? ((gg + 1) << 6) + u : (gg << 6) + u;
        float nc0 = cC0[nx], nc1 = cC1[nx], nc2 = cC2[nx];
        float noA = cOA[nx], noB = cOB[nx];
        if (g < gmax){
          float up1 = wshr1(A);
          float up2 = wshr1(up1);
          int i0 = 2 * g - u;
          float Amid = logadd2(A + oAv, up1 + oBv);
          bool tv1 = ((unsigned)(i0 + 1) < 256u);
          Amid = tv1 ? Amid : NEGF;
          float a0 = A + c0v, a1 = up1 + c1v, a2 = up2 + c2v;
          float m3 = fmaxf(fmaxf(a0, a1), a2);          // v_max3
          float s3 = __builtin_amdgcn_exp2f(a0 - m3) + __builtin_amdgcn_exp2f(a1 - m3)
                   + __builtin_amdgcn_exp2f(a2 - m3);
          float Anew = m3 + __builtin_amdgcn_logf(s3);
          bool tv2 = ((unsigned)(i0 + 2) < 256u);
          Anew = tv2 ? Anew : NEGF;
          if (isTL && (i0 + 1) == til) res = Amid + fb;
          if (isTL && (i0 + 2) == til) res = Anew + fb;
          if (u == 63){
            if (tv1) sS[i0 + 1] = Amid;
            if (tv2) sS[i0 + 2] = Anew;
          }
          A = Anew;
        }
        c0v = nc0; c1v = nc1; c2v = nc2; oAv = noA; oBv = noB;
      }
    }
    __syncthreads();                   // protect cArr from next fill
  }

  if (tid >= 64) return;

  if (cap64){
    const float* pb64 = sbb + (64 << 8);
    const float* pl63 = slb + (63 << 8);
    float A64 = sS[0] + pl63[0];       // alpha[0][64]
    for (int t = 1; t <= til; t++)
      A64 = logadd2(A64 + pb64[t - 1], sS[t] + pl63[t]);
    if (u == 0) res = A64 + pb64[til];
  }

  // butterfly-sum broadcasts the single captured value (others hold 0)
  res += __shfl_xor(res, 1, 64);
  res += __shfl_xor(res, 2, 64);
  res += __shfl_xor(res, 4, 64);
  res += __shfl_xor(res, 8, 64);
  res += __shfl_xor(res, 16, 64);
  res += __shfl_xor(res, 32, 64);
  if (u == 0) atomicAdd(out, -0.17328679513998632f * res);  // -0.25 * ln2 (log2->ln)
}

extern "C" void kernel_launch(void* const* d_in, const int* in_sizes, int n_in,
                              void* d_out, int out_size, void* d_ws, size_t ws_size,
                              hipStream_t stream)
{
  (void)in_sizes; (void)n_in; (void)out_size; (void)ws_size;
  const float* inputs = (const float*)d_in[0];   // (4,256,80)
  const float* W_enc  = (const float*)d_in[1];   // (80,512)
  const float* emb    = (const float*)d_in[2];   // (1024,512)
  const float* W_jenc = (const float*)d_in[3];   // (512,512)
  const float* W_jdec = (const float*)d_in[4];   // (512,512)
  const float* b_j    = (const float*)d_in[5];   // (512)
  const float* W_out  = (const float*)d_in[6];   // (512,1024)
  const float* b_out  = (const float*)d_in[7];   // (1024)
  const int* targets  = (const int*)d_in[8];     // (4,64)
  const int* in_len   = (const int*)d_in[9];     // (4)
  const int* tgt_len  = (const int*)d_in[10];    // (4)

  char* w = (char*)d_ws;
  auto alloc = [&](size_t bytes){ char* p = w; w += (bytes + 255) & ~(size_t)255; return p; };
  float* e       = (float*)alloc((size_t)1024 * 512 * 4);
  float* dmatb   = (float*)alloc((size_t)260 * 512 * 4);
  float* blank_g = (float*)alloc((size_t)cM * 4);
  float* lbl_g   = (float*)alloc((size_t)cM * 4);
  float* S       = (float*)alloc((size_t)cM * 4);
  uchar_t* Hbf8  = (uchar_t*)alloc((size_t)520 * 65536);
  uchar_t* WTf8  = (uchar_t*)alloc((size_t)4 * 131072);

  k_pre<<<739, 256, 0, stream>>>(inputs, W_enc, W_jenc, emb, targets, W_jdec, b_j,
                                 dmatb, e, W_out, WTf8, S, (float*)d_out);
  k_hf<<<1040, 256, 0, stream>>>(e, dmatb, Hbf8);
  k_joint<<<4160, 256, 0, stream>>>(Hbf8, WTf8, b_out, targets, S, blank_g, lbl_g);
  k_dp<<<4, 256, 0, stream>>>(S, blank_g, lbl_g, in_len, tgt_len, (float*)d_out);
}

// Round 19
// 201.552 us; speedup vs baseline: 1.1033x; 1.0000x over previous
//
#include <hip/hip_runtime.h>
#include <stdint.h>

#define NEGF (-1e30f)

typedef unsigned short ushort_t;
typedef unsigned char uchar_t;
typedef __attribute__((ext_vector_type(2))) long v2i64;
typedef __attribute__((ext_vector_type(4))) float f32x4;

constexpr int cB = 4, cT = 256, cU = 64, cU1 = 65, cV = 1024, cF = 80, cH = 512, cJ = 512;
constexpr int cM = cB * cT * cU1; // 66560
constexpr int cTU = cT * cU1;     // 16640 (per-batch (u,t) plane: u*256+t)
constexpr float LOG2E = 1.4426950408889634f;

// Padé(2,2) tanh + clamp: max err ~0.016, far below fp8-e4m3 half-step; no v_exp.
__device__ __forceinline__ float tanh_fast(float x){
  float t = x * x;
  float num = x * (27.f + t);
  float den = fmaf(9.f, t, 27.f);
  float r = num * __builtin_amdgcn_rcpf(den);
  return fminf(1.f, fmaxf(-1.f, r));
}

// log2-domain logadd: v_exp_f32/v_log_f32 ARE base-2 -> no ln2 scaling muls.
__device__ __forceinline__ float logadd2(float x, float y){
  float m = fmaxf(x, y);
  return m + __builtin_amdgcn_logf(1.f + __builtin_amdgcn_exp2f(-fabsf(x - y)));
}

// wave shift-right-by-1 via DPP (lane i <- lane i-1); invalid lane 0 reads 0.0f
// (bound_ctrl:0). 2-cycle VALU op on k_dp's serial A->A critical path.
__device__ __forceinline__ float wshr1(float x){
  return __int_as_float(__builtin_amdgcn_mov_dpp(__float_as_int(x),
                                                 0x138, 0xF, 0xF, true));
}

__device__ __forceinline__ int pk8(float a, float b, float c, float d){
  int v = __builtin_amdgcn_cvt_pk_fp8_f32(a, b, 0, false);
  v = __builtin_amdgcn_cvt_pk_fp8_f32(c, d, v, true);
  return v;
}

// ------------- fused prologue: 4 independent jobs in one dispatch -------------
// bid 0..511  : e[4 rows x 256 cols] = (inputs @ W_enc) @ W_jenc
// bid 512..641: dmatb(260,512) = emb[padded] @ W_jdec + b_j
// bid 642..673: WTf8 fp8 fragment-order transpose of 32*W_out (2-ks-packed, K=32)
// bid 674..738: zero S[cM]; bid 674 also zeroes out[0] (k_dp atomic target)
__global__ __launch_bounds__(256) void k_pre(
    const float* __restrict__ inputs,
    const float* __restrict__ W_enc, const float* __restrict__ W_jenc,
    const float* __restrict__ emb, const int* __restrict__ targets,
    const float* __restrict__ W_jdec, const float* __restrict__ b_j,
    float* __restrict__ dmatb, float* __restrict__ e,
    const float* __restrict__ W_out, uchar_t* __restrict__ WTf8,
    float* __restrict__ S, float* __restrict__ out_loss)
{
  __shared__ float sA[4][512];
  __shared__ float sIn[4][80];
  int bid = blockIdx.x;
  int tid = threadIdx.x;

  if (bid < 512){
    // ---- e rows m0..m0+3, cols half*256..+255 ----
    int m0 = (bid >> 1) * 4;
    int half = bid & 1;
    for (int i = tid; i < 320; i += 256)
      sIn[i / 80][i % 80] = inputs[m0 * 80 + i];
    __syncthreads();
    int c0 = tid, c1 = tid + 256;
    float a00 = 0.f, a01 = 0.f, a10 = 0.f, a11 = 0.f;
    float a20 = 0.f, a21 = 0.f, a30 = 0.f, a31 = 0.f;
#pragma unroll 8
    for (int k = 0; k < 80; k++){
      float w0 = W_enc[(size_t)k * 512 + c0];
      float w1 = W_enc[(size_t)k * 512 + c1];
      a00 = fmaf(sIn[0][k], w0, a00); a01 = fmaf(sIn[0][k], w1, a01);
      a10 = fmaf(sIn[1][k], w0, a10); a11 = fmaf(sIn[1][k], w1, a11);
      a20 = fmaf(sIn[2][k], w0, a20); a21 = fmaf(sIn[2][k], w1, a21);
      a30 = fmaf(sIn[3][k], w0, a30); a31 = fmaf(sIn[3][k], w1, a31);
    }
    sA[0][c0] = a00; sA[0][c1] = a01;
    sA[1][c0] = a10; sA[1][c1] = a11;
    sA[2][c0] = a20; sA[2][c1] = a21;
    sA[3][c0] = a30; sA[3][c1] = a31;
    __syncthreads();
    int col = half * 256 + tid;
    float b0 = 0.f, b1 = 0.f, b2 = 0.f, b3 = 0.f;
#pragma unroll 8
    for (int k = 0; k < 512; k++){
      float w = W_jenc[(size_t)k * 512 + col];
      b0 = fmaf(sA[0][k], w, b0);
      b1 = fmaf(sA[1][k], w, b1);
      b2 = fmaf(sA[2][k], w, b2);
      b3 = fmaf(sA[3][k], w, b3);
    }
    e[(size_t)(m0 + 0) * 512 + col] = b0;
    e[(size_t)(m0 + 1) * 512 + col] = b1;
    e[(size_t)(m0 + 2) * 512 + col] = b2;
    e[(size_t)(m0 + 3) * 512 + col] = b3;
  } else if (bid < 642){
    // ---- dmatb = emb[padded] @ W_jdec + b_j ----
    int id = bid - 512;                  // 0..129
    int bx = id & 1, by = id >> 1;
    int m0 = by * 4;
    int col = bx * 256 + tid;
    for (int i = tid; i < 4 * 512; i += 256){
      int r = i >> 9, c = i & 511;
      int row = m0 + r;
      int b = row / cU1, u = row % cU1;
      int src = (u == 0) ? 0 : targets[b * cU + (u - 1)];
      sA[r][c] = emb[(size_t)src * cH + c];
    }
    __syncthreads();
    float a0 = 0.f, a1 = 0.f, a2 = 0.f, a3 = 0.f;
#pragma unroll 8
    for (int k = 0; k < 512; k++){
      float bv = W_jdec[(size_t)k * cJ + col];
      a0 = fmaf(sA[0][k], bv, a0);
      a1 = fmaf(sA[1][k], bv, a1);
      a2 = fmaf(sA[2][k], bv, a2);
      a3 = fmaf(sA[3][k], bv, a3);
    }
    float bb = b_j[col];
    dmatb[(size_t)(m0 + 0) * cJ + col] = a0 + bb;
    dmatb[(size_t)(m0 + 1) * cJ + col] = a1 + bb;
    dmatb[(size_t)(m0 + 2) * cJ + col] = a2 + bb;
    dmatb[(size_t)(m0 + 3) * cJ + col] = a3 + bb;
  } else if (bid < 674){
    // ---- WTf8[((bn4*8+ksp)*16 + nt16)*1024 + lane*16]  (K=32, 2-ks-packed) ----
    int id = bid - 642;                  // 0..31
    int bn = id & 3, ksp = id >> 2;      // ksp 0..7
    int lane = tid & 63, nth = tid >> 6;
    int c16 = lane & 15, quad = lane >> 4;
    int jA = ksp * 64 + quad * 8;
#pragma unroll
    for (int i = 0; i < 4; i++){
      int nt16 = nth * 4 + i;
      int n = bn * 256 + nt16 * 16 + c16;
      unsigned int p[4];
#pragma unroll
      for (int h = 0; h < 4; h++){
        int j0 = jA + (h >> 1) * 32 + (h & 1) * 4;
        float w0 = W_out[(size_t)(j0 + 0) * cV + n] * 32.f;
        float w1 = W_out[(size_t)(j0 + 1) * cV + n] * 32.f;
        float w2 = W_out[(size_t)(j0 + 2) * cV + n] * 32.f;
        float w3 = W_out[(size_t)(j0 + 3) * cV + n] * 32.f;
        p[h] = (unsigned)pk8(w0, w1, w2, w3);
      }
      uint4 pack; pack.x = p[0]; pack.y = p[1]; pack.z = p[2]; pack.w = p[3];
      *(uint4*)(WTf8 + (((size_t)(bn * 8 + ksp) * 16 + nt16) * 64 + lane) * 16) = pack;
    }
  } else {
    // ---- zero S: 65 blocks x 256 thr x 4 floats = 66560 ----
    int i = (bid - 674) * 1024 + tid * 4;
    float4 z; z.x = 0.f; z.y = 0.f; z.z = 0.f; z.w = 0.f;
    *(float4*)(S + i) = z;
    if (bid == 674 && tid == 0) out_loss[0] = 0.f;
  }
}

// ------------- H fp8 fragment-order (K=32), t-minor, coalesced via LDS bounce -------------
__global__ __launch_bounds__(256) void k_hf(const float* __restrict__ e,
                                            const float* __restrict__ dmatb,
                                            uchar_t* __restrict__ Hbf8){
  __shared__ uchar_t sH[16 * 520];    // 16 rows x 512 B, pad 8 B
  int tid = threadIdx.x;
  int wid = tid >> 6, lane = tid & 63;
  int c16 = lane & 15, quad = lane >> 4;
  int bm = blockIdx.x >> 1;
  int mgh = blockIdx.x & 1;           // mg half: 0 -> mg 0..3, 1 -> mg 4..7
  int bu = bm >> 1, thalf = bm & 1;
  int b = bu / cU1;
  int t0 = thalf * 128;

  float dj[8];
  const float4* dp = (const float4*)(dmatb + (size_t)bu * cJ + lane * 8);
  float4 dA = dp[0], dB = dp[1];
  dj[0] = dA.x; dj[1] = dA.y; dj[2] = dA.z; dj[3] = dA.w;
  dj[4] = dB.x; dj[5] = dB.y; dj[6] = dB.z; dj[7] = dB.w;

  const float* erow0 = e + ((size_t)(b * cT + t0)) * cJ + lane * 8;
  uchar_t* outb = Hbf8 + (size_t)bm * 65536 + lane * 16;

  for (int mg = mgh * 4; mg < mgh * 4 + 4; mg++){
#pragma unroll
    for (int rr = 0; rr < 4; rr++){
      int rloc = wid * 4 + rr;
      const float* ep = erow0 + ((size_t)(mg * 16 + rloc)) * cJ;
      float4 e0 = *(const float4*)ep;
      float4 e1 = *(const float4*)(ep + 4);
      int v0 = pk8(tanh_fast(e0.x + dj[0]), tanh_fast(e0.y + dj[1]),
                   tanh_fast(e0.z + dj[2]), tanh_fast(e0.w + dj[3]));
      int v1 = pk8(tanh_fast(e1.x + dj[4]), tanh_fast(e1.y + dj[5]),
                   tanh_fast(e1.z + dj[6]), tanh_fast(e1.w + dj[7]));
      uint2 pk; pk.x = (unsigned)v0; pk.y = (unsigned)v1;
      *(uint2*)(sH + rloc * 520 + lane * 8) = pk;
    }
    __syncthreads();
#pragma unroll
    for (int q = 0; q < 2; q++){
      int ksp = wid * 2 + q;
      uint2 lo = *(const uint2*)(sH + c16 * 520 + ksp * 64 + quad * 8);
      uint2 hi = *(const uint2*)(sH + c16 * 520 + ksp * 64 + 32 + quad * 8);
      uint4 pack; pack.x = lo.x; pack.y = lo.y; pack.z = hi.x; pack.w = hi.y;
      *(uint4*)(outb + ((size_t)ksp * 8 + mg) * 1024) = pack;
    }
    __syncthreads();
  }
}

// ------------- joint GEMM fp8 K=32: 64x64 wave tile, LDS-partial epilogue -------------
// FINAL config: r14/r16 body (measured 52.6/52.7/52.8us across three runs).
// 52.6us = fp8-MFMA floor 34us + ~19us un-hideable L2-issue/epilogue at
// 3 blocks/CU. All register-budget-compatible schedules exhausted
// (MX/LDS-staging/multi-strip spill past the ~80-VGPR wall; source/asm
// pipelining and shape-switch neutral-to-negative).
__global__ __launch_bounds__(256, 3) void k_joint(
    const uchar_t* __restrict__ Hbf8, const uchar_t* __restrict__ WTf8,
    const float* __restrict__ b_out, const int* __restrict__ targets,
    float* __restrict__ S,
    float* __restrict__ blank_g, float* __restrict__ lbl_g)
{
  __shared__ float redP[2][128][19];   // 19456 B

  int tid = threadIdx.x;
  int wid = tid >> 6, lane = tid & 63;
  int quad = lane >> 4, c16 = lane & 15;
  int wm = wid & 1, wn = wid >> 1;
  int bid = blockIdx.x;
  int bm = ((bid >> 6) << 3) + (bid & 7);
  int bn = (bid >> 3) & 7;                       // 128-col strip
  int bu = bm >> 1, thalf = bm & 1;
  int b = bu / cU1, u = bu - b * cU1;
  int tg = (u < cU) ? targets[b * cU + u] : -1;
  int lin0 = bu * cT + thalf * 128;              // (b,u,t)-linear base

  f32x4 acc[4][4];
#pragma unroll
  for (int i = 0; i < 4; i++)
#pragma unroll
    for (int j = 0; j < 4; j++)
      acc[i][j] = (f32x4){0.f, 0.f, 0.f, 0.f};

  const uchar_t* aP = Hbf8 + (size_t)bm * 65536 + (wm * 4) * 1024 + lane * 16;
  const uchar_t* bP = WTf8 + (size_t)(bn >> 1) * 131072 + ((bn & 1) * 8 + wn * 4) * 1024 + lane * 16;

  v2i64 afX[4], bfX[4], afY[4], bfY[4];
#pragma unroll
  for (int mt = 0; mt < 4; mt++) afX[mt] = *(const v2i64*)(aP + mt * 1024);
#pragma unroll
  for (int nt = 0; nt < 4; nt++) bfX[nt] = *(const v2i64*)(bP + nt * 1024);

#pragma unroll
  for (int k2 = 0; k2 < 4; k2++){
    // ---- issue loads for ksp = 2*k2+1 (Y) a full MFMA stage early ----
    {
      size_t kY = (size_t)(2 * k2 + 1);
#pragma unroll
      for (int mt = 0; mt < 4; mt++) afY[mt] = *(const v2i64*)(aP + kY * 8192 + mt * 1024);
#pragma unroll
      for (int nt = 0; nt < 4; nt++) bfY[nt] = *(const v2i64*)(bP + kY * 16384 + nt * 1024);
    }
    // ---- MFMA on X (covers Y's load latency) ----
#pragma unroll
    for (int h = 0; h < 2; h++)
#pragma unroll
      for (int mt = 0; mt < 4; mt++)
#pragma unroll
        for (int nt = 0; nt < 4; nt++)
          acc[mt][nt] = __builtin_amdgcn_mfma_f32_16x16x32_fp8_fp8(afX[mt][h], bfX[nt][h], acc[mt][nt], 0, 0, 0);
    // ---- issue loads for ksp = 2*k2+2 (X), statically guarded ----
    if (k2 < 3){
      size_t kX = (size_t)(2 * k2 + 2);
#pragma unroll
      for (int mt = 0; mt < 4; mt++) afX[mt] = *(const v2i64*)(aP + kX * 8192 + mt * 1024);
#pragma unroll
      for (int nt = 0; nt < 4; nt++) bfX[nt] = *(const v2i64*)(bP + kX * 16384 + nt * 1024);
    }
    // ---- MFMA on Y (covers X's load latency) ----
#pragma unroll
    for (int h = 0; h < 2; h++)
#pragma unroll
      for (int mt = 0; mt < 4; mt++)
#pragma unroll
        for (int nt = 0; nt < 4; nt++)
          acc[mt][nt] = __builtin_amdgcn_mfma_f32_16x16x32_fp8_fp8(afY[mt][h], bfY[nt][h], acc[mt][nt], 0, 0, 0);
  }

  float bv[4];
#pragma unroll
  for (int nt = 0; nt < 4; nt++) bv[nt] = b_out[bn * 128 + (wn * 4 + nt) * 16 + c16] * LOG2E;

  bool ownL = (tg >= 0) && ((tg >> 7) == bn) && (((tg >> 6) & 1) == wn);
  int ntO = (tg >> 4) & 3;
  int tgc = tg & 15;
  const float descale2 = LOG2E / 32.f;  // undo *32 on W_out fp8 AND go log2-domain

#pragma unroll
  for (int mt = 0; mt < 4; mt++){
#pragma unroll
    for (int r = 0; r < 4; r++){
      int rl = wm * 64 + mt * 16 + quad * 4 + r;  // C/D: col=lane&15, row=quad*4+reg (m89)
      float l[4];
#pragma unroll
      for (int nt = 0; nt < 4; nt++) l[nt] = fmaf(acc[mt][nt][r], descale2, bv[nt]);
      if (bn == 0 && wn == 0 && c16 == 0) blank_g[lin0 + rl] = l[0];
      if (ownL && c16 == tgc){
        float v = l[0];
#pragma unroll
        for (int k = 1; k < 4; k++) v = (ntO == k) ? l[k] : v;
        lbl_g[lin0 + rl] = v;
      }
      redP[wn][rl][c16] = __builtin_amdgcn_exp2f(l[0]) + __builtin_amdgcn_exp2f(l[1])
                        + __builtin_amdgcn_exp2f(l[2]) + __builtin_amdgcn_exp2f(l[3]);
    }
  }
  __syncthreads();
  if (tid < 128){
    float a = 0.f;
#pragma unroll
    for (int j = 0; j < 16; j++) a += redP[0][tid][j] + redP[1][tid][j];
    atomicAdd(&S[lin0 + tid], a);
  }
}

// ------------- RNN-T alpha DP: phase-split producer/consumer + gmax truncation -------------
__global__ __launch_bounds__(256) void k_dp(
    const float* __restrict__ S, const float* __restrict__ blank_g,
    const float* __restrict__ lbl_g,
    const int* __restrict__ in_len, const int* __restrict__ tgt_len,
    float* __restrict__ out)
{
  constexpr int G = 16;        // g-steps per chunk
  __shared__ float sbb[cTU];   // 65 KB, (u,t): index u*256+t  (log2 domain)
  __shared__ float slb[cTU];   // 65 KB
  __shared__ float sS[256];    // alpha[t][63] history (lane 63)
  __shared__ float cC0[G * 64], cC1[G * 64], cC2[G * 64];
  __shared__ float cOA[G * 64], cOB[G * 64];
  int tid = threadIdx.x;
  int b = blockIdx.x;
  int tl  = tgt_len[b];                // 32..64
  size_t base = (size_t)b * cTU;
  for (int i = tid; i < cTU / 4; i += 256){
    int row = i >> 6;                  // float4 never crosses a 256-elem row
    if (row > tl) continue;            // rows > tl unread by any live lane
    float4 sv = ((const float4*)(S + base))[i];
    float4 bvv = ((const float4*)(blank_g + base))[i];
    float4 ls;
    ls.x = __builtin_amdgcn_logf(sv.x); ls.y = __builtin_amdgcn_logf(sv.y);
    ls.z = __builtin_amdgcn_logf(sv.z); ls.w = __builtin_amdgcn_logf(sv.w);
    float4 bo;
    bo.x = bvv.x - ls.x; bo.y = bvv.y - ls.y;
    bo.z = bvv.z - ls.z; bo.w = bvv.w - ls.w;
    ((float4*)sbb)[i] = bo;
    float4 lo;
    if (row < tl){
      float4 lv = ((const float4*)(lbl_g + base))[i];
      lo.x = lv.x - ls.x; lo.y = lv.y - ls.y;
      lo.z = lv.z - ls.z; lo.w = lv.w - ls.w;
    } else {
      lo.x = NEGF; lo.y = NEGF; lo.z = NEGF; lo.w = NEGF;
    }
    ((float4*)slb)[i] = lo;
  }
  __syncthreads();

  int til = in_len[b] - 1;
  bool cap64 = (tl == 64);
  int u = tid;                         // meaningful for tid<64
  bool isTL = (u == tl);
  float fb = (tid < 64) ? sbb[(u << 8) + til] : 0.f;

  // last diagonal needed: res captures at g<=ceil((til+tl)/2); sS fills
  // (cap64 path) need g<=ceil((til+62)/2). +2 safety; cap at 159.
  int need = til + tl;
  if (cap64 && til + 62 > need) need = til + 62;
  int gmax = (need >> 1) + 2;
  if (gmax > 159) gmax = 159;
  int nph = (gmax + G - 1) / G;        // block-uniform

  float A = (u == 0) ? 0.f : NEGF;     // alpha on even diagonal d = 2g (log2)
  float res = 0.f;

  auto ld = [&](const float* p, int i, bool ok) -> float {
    float x = p[i & 255];              // wrap stays inside sbb/slb
    return (ok & ((unsigned)i < 256u)) ? x : NEGF;
  };

  for (int p = 0; p < nph; p++){
    // ---- fill phase: all 256 threads precompute C/o arrays for this chunk ----
    for (int w = tid; w < G * 64; w += 256){
      int gg = w >> 6, uu = w & 63;
      int g = p * G + gg;              // g>=gmax entries filled but never read
      int i0 = 2 * g - uu;
      bool v1 = (uu >= 1), v2 = (uu >= 2);
      const float* pbu  = sbb + (uu << 8);
      const float* pbu1 = sbb + ((v1 ? uu - 1 : 0) << 8);
      const float* plu1 = slb + ((v1 ? uu - 1 : 0) << 8);
      const float* plu2 = slb + ((v2 ? uu - 2 : 0) << 8);
      float o0 = ld(pbu,  i0,     true);   // bb[t-2][u]
      float o1 = ld(pbu,  i0 + 1, true);   // bb[t-1][u]
      float o2 = ld(plu1, i0 + 1, v1);     // lb[t-1][u-1]
      float o3 = ld(pbu1, i0 + 1, v1);     // bb[t-1][u-1]
      float o4 = ld(plu1, i0 + 2, v1);     // lb[t][u-1]
      float o5 = ld(plu2, i0 + 2, v2);     // lb[t][u-2]
      cC0[w] = o0 + o1;
      cC1[w] = logadd2(o2 + o1, o3 + o4);
      cC2[w] = o5 + o4;
      cOA[w] = o0;
      cOB[w] = o2;
    }
    __syncthreads();
    // ---- consume phase: wave 0 runs G recurrence steps ----
    if (tid < 64){
      float c0v = cC0[u], c1v = cC1[u], c2v = cC2[u];
      float oAv = cOA[u], oBv = cOB[u];
#pragma unroll
      for (int gg = 0; gg < G; gg++){
        int g = p * G + gg;
        int nx = (gg + 1 < G) ? ((gg + 1) << 6) + u : (gg << 6) + u;
        float nc0 = cC0[nx], nc1 = cC1[nx], nc2 = cC2[nx];
        float noA = cOA[nx], noB = cOB[nx];
        if (g < gmax){
          float up1 = wshr1(A);
          float up2 = wshr1(up1);
          int i0 = 2 * g - u;
          float Amid = logadd2(A + oAv, up1 + oBv);
          bool tv1 = ((unsigned)(i0 + 1) < 256u);
          Amid = tv1 ? Amid : NEGF;
          float a0 = A + c0v, a1 = up1 + c1v, a2 = up2 + c2v;
          float m3 = fmaxf(fmaxf(a0, a1), a2);          // v_max3
          float s3 = __builtin_amdgcn_exp2f(a0 - m3) + __builtin_amdgcn_exp2f(a1 - m3)
                   + __builtin_amdgcn_exp2f(a2 - m3);
          float Anew = m3 + __builtin_amdgcn_logf(s3);
          bool tv2 = ((unsigned)(i0 + 2) < 256u);
          Anew = tv2 ? Anew : NEGF;
          if (isTL && (i0 + 1) == til) res = Amid + fb;
          if (isTL && (i0 + 2) == til) res = Anew + fb;
          if (u == 63){
            if (tv1) sS[i0 + 1] = Amid;
            if (tv2) sS[i0 + 2] = Anew;
          }
          A = Anew;
        }
        c0v = nc0; c1v = nc1; c2v = nc2; oAv = noA; oBv = noB;
      }
    }
    __syncthreads();                   // protect cArr from next fill
  }

  if (tid >= 64) return;

  if (cap64){
    const float* pb64 = sbb + (64 << 8);
    const float* pl63 = slb + (63 << 8);
    float A64 = sS[0] + pl63[0];       // alpha[0][64]
    for (int t = 1; t <= til; t++)
      A64 = logadd2(A64 + pb64[t - 1], sS[t] + pl63[t]);
    if (u == 0) res = A64 + pb64[til];
  }

  // butterfly-sum broadcasts the single captured value (others hold 0)
  res += __shfl_xor(res, 1, 64);
  res += __shfl_xor(res, 2, 64);
  res += __shfl_xor(res, 4, 64);
  res += __shfl_xor(res, 8, 64);
  res += __shfl_xor(res, 16, 64);
  res += __shfl_xor(res, 32, 64);
  if (u == 0) atomicAdd(out, -0.17328679513998632f * res);  // -0.25 * ln2 (log2->ln)
}

extern "C" void kernel_launch(void* const* d_in, const int* in_sizes, int n_in,
                              void* d_out, int out_size, void* d_ws, size_t ws_size,
                              hipStream_t stream)
{
  (void)in_sizes; (void)n_in; (void)out_size; (void)ws_size;
  const float* inputs = (const float*)d_in[0];   // (4,256,80)
  const float* W_enc  = (const float*)d_in[1];   // (80,512)
  const float* emb    = (const float*)d_in[2];   // (1024,512)
  const float* W_jenc = (const float*)d_in[3];   // (512,512)
  const float* W_jdec = (const float*)d_in[4];   // (512,512)
  const float* b_j    = (const float*)d_in[5];   // (512)
  const float* W_out  = (const float*)d_in[6];   // (512,1024)
  const float* b_out  = (const float*)d_in[7];   // (1024)
  const int* targets  = (const int*)d_in[8];     // (4,64)
  const int* in_len   = (const int*)d_in[9];     // (4)
  const int* tgt_len  = (const int*)d_in[10];    // (4)

  char* w = (char*)d_ws;
  auto alloc = [&](size_t bytes){ char* p = w; w += (bytes + 255) & ~(size_t)255; return p; };
  float* e       = (float*)alloc((size_t)1024 * 512 * 4);
  float* dmatb   = (float*)alloc((size_t)260 * 512 * 4);
  float* blank_g = (float*)alloc((size_t)cM * 4);
  float* lbl_g   = (float*)alloc((size_t)cM * 4);
  float* S       = (float*)alloc((size_t)cM * 4);
  uchar_t* Hbf8  = (uchar_t*)alloc((size_t)520 * 65536);
  uchar_t* WTf8  = (uchar_t*)alloc((size_t)4 * 131072);

  k_pre<<<739, 256, 0, stream>>>(inputs, W_enc, W_jenc, emb, targets, W_jdec, b_j,
                                 dmatb, e, W_out, WTf8, S, (float*)d_out);
  k_hf<<<1040, 256, 0, stream>>>(e, dmatb, Hbf8);
  k_joint<<<4160, 256, 0, stream>>>(Hbf8, WTf8, b_out, targets, S, blank_g, lbl_g);
  k_dp<<<4, 256, 0, stream>>>(S, blank_g, lbl_g, in_len, tgt_len, (float*)d_out);
}